// Round 3
// baseline (705.546 us; speedup 1.0000x reference)
//
#include <hip/hip_runtime.h>
#include <hip/hip_bf16.h>
#include <stdint.h>

#define BATCH 2
#define SEQ   2048
#define DIM   2048
#define NH    32
#define NKV   8
#define HD    64
#define QKVN  3072   // DIM + 2*NKV*HD
#define MROWS 4096   // BATCH*SEQ

typedef __bf16 bf16x8 __attribute__((ext_vector_type(8)));
typedef float  f32x4  __attribute__((ext_vector_type(4)));
typedef unsigned short ushort8v __attribute__((ext_vector_type(8)));

typedef __attribute__((address_space(3))) void lds_void;
typedef const __attribute__((address_space(1))) void gbl_void;

__device__ __forceinline__ void gload_lds16(const void* g, void* l) {
    __builtin_amdgcn_global_load_lds((gbl_void*)g, (lds_void*)l, 16, 0, 0);
}

// ---------------- fp32 -> bf16 convert (vectorized) ----------------
__global__ void cvt_f32_bf16(const float* __restrict__ in,
                             __hip_bfloat16* __restrict__ out, int n) {
    int i = (blockIdx.x * 256 + threadIdx.x) * 4;
    if (i >= n) return;
    const float4 v = *reinterpret_cast<const float4*>(in + i);
    union { ushort4 u; __hip_bfloat16 h[4]; } o;
    o.h[0] = __float2bfloat16(v.x);
    o.h[1] = __float2bfloat16(v.y);
    o.h[2] = __float2bfloat16(v.z);
    o.h[3] = __float2bfloat16(v.w);
    *reinterpret_cast<ushort4*>(out + i) = o.u;
}

// ---------------- GEMM: C[M,N] = A[M,K] * B[N,K]^T  (m97 structure) -----
__device__ __forceinline__ void store_out(float* p, float v) { *p = v; }
__device__ __forceinline__ void store_out(__hip_bfloat16* p, float v) { *p = __float2bfloat16(v); }

template <typename OUT_T>
__global__ __launch_bounds__(256) void gemm_bt(
    const __hip_bfloat16* __restrict__ A,
    const __hip_bfloat16* __restrict__ B,
    OUT_T* __restrict__ C,
    int M, int N, int K)
{
    __shared__ __align__(16) __hip_bfloat16 As[128 * 32];
    __shared__ __align__(16) __hip_bfloat16 Bs[128 * 32];
    const int tid  = threadIdx.x;
    const int lane = tid & 63;
    const int wave = tid >> 6;
    const int wr = wave >> 1, wc = wave & 1;
    const int lr = lane & 15, lg = lane >> 4;
    const size_t tm = (size_t)blockIdx.x * 128;
    const size_t tn = (size_t)blockIdx.y * 128;

    f32x4 acc[4][4] = {};

    const int srow  = tid >> 2;        // 0..63
    const int scol  = (tid & 3) * 8;   // elem offset in K-step
    const int wbase = wave * 512;      // elems (1024B per wave chunk)

    const __hip_bfloat16* pa = As + (wr * 64 + lr) * 32 + lg * 8;
    const __hip_bfloat16* pb = Bs + (wc * 64 + lr) * 32 + lg * 8;

    for (int k0 = 0; k0 < K; k0 += 32) {
        const __hip_bfloat16* gA = A + (tm + srow) * (size_t)K + k0 + scol;
        const __hip_bfloat16* gB = B + (tn + srow) * (size_t)K + k0 + scol;
        gload_lds16(gA,                 (void*)(As + wbase));
        gload_lds16(gA + (size_t)64*K,  (void*)(As + 2048 + wbase));
        gload_lds16(gB,                 (void*)(Bs + wbase));
        gload_lds16(gB + (size_t)64*K,  (void*)(Bs + 2048 + wbase));
        __syncthreads();   // compiler drains vmcnt before s_barrier
        bf16x8 af[4], bfr[4];
        #pragma unroll
        for (int m = 0; m < 4; ++m) af[m]  = *reinterpret_cast<const bf16x8*>(pa + m * 512);
        #pragma unroll
        for (int n = 0; n < 4; ++n) bfr[n] = *reinterpret_cast<const bf16x8*>(pb + n * 512);
        #pragma unroll
        for (int m = 0; m < 4; ++m)
            #pragma unroll
            for (int n = 0; n < 4; ++n)
                acc[m][n] = __builtin_amdgcn_mfma_f32_16x16x32_bf16(af[m], bfr[n], acc[m][n], 0, 0, 0);
        __syncthreads();
    }

    #pragma unroll
    for (int m = 0; m < 4; ++m)
        #pragma unroll
        for (int n = 0; n < 4; ++n)
            #pragma unroll
            for (int r = 0; r < 4; ++r) {
                size_t row = tm + wr * 64 + m * 16 + lg * 4 + r;
                size_t col = tn + wc * 64 + n * 16 + lr;
                store_out(&C[row * (size_t)N + col], acc[m][n][r]);
            }
}

// ---------------- RoPE (interleaved pairs) + repack ----------------
// mul: extra scale folded into the rotated output (Q gets 1/sqrt(HD)=0.125,
// an exact power of two -> no added bf16 rounding error; K gets 1.0).
__global__ void rope_qk(const __hip_bfloat16* __restrict__ qkv,
                        const float* __restrict__ fcos,
                        const float* __restrict__ fsin,
                        __hip_bfloat16* __restrict__ outp,
                        int nheads, int col_off, float mul) {
    int idx = blockIdx.x * 256 + threadIdx.x;
    int i  = idx & 31;
    int s  = (idx >> 5) & (SEQ - 1);
    int bh = idx >> 16;             // SEQ*32 = 65536
    int h  = bh % nheads;
    const __hip_bfloat16* src = qkv + ((size_t)(bh / nheads) * SEQ + s) * QKVN
                                    + col_off + h * HD + 2 * i;
    union { unsigned int u; __hip_bfloat16 h2[2]; } in_, out_;
    in_.u = *reinterpret_cast<const unsigned int*>(src);
    float t0 = __bfloat162float(in_.h2[0]);
    float t1 = __bfloat162float(in_.h2[1]);
    float c  = fcos[s * 32 + i] * mul;
    float sn = fsin[s * 32 + i] * mul;
    out_.h2[0] = __float2bfloat16(t0 * c - t1 * sn);
    out_.h2[1] = __float2bfloat16(t0 * sn + t1 * c);
    *reinterpret_cast<unsigned int*>(outp + ((size_t)bh * SEQ + s) * HD + 2 * i) = out_.u;
}

// V: [b][s][2560 + kh*64 + d] -> Vt[b][kh][d][s]  (LDS tile transpose)
__global__ __launch_bounds__(256) void v_repack(const __hip_bfloat16* __restrict__ qkv,
                                                __hip_bfloat16* __restrict__ vt) {
    __shared__ unsigned short tile[64][66];
    int blk = blockIdx.x;              // 2*8*32 = 512
    int st = blk & 31;
    int kh = (blk >> 5) & 7;
    int b  = blk >> 8;
    int s0 = st * 64;
    int t  = threadIdx.x;
    int r  = t >> 2;
    #pragma unroll
    for (int it = 0; it < 2; ++it) {
        int chunk = (t & 3) + it * 4;   // 0..7
        const __hip_bfloat16* src = qkv + ((size_t)(b * SEQ + s0 + r)) * QKVN
                                        + 2560 + kh * HD + chunk * 8;
        ushort8v v = *reinterpret_cast<const ushort8v*>(src);
        #pragma unroll
        for (int j = 0; j < 8; ++j) tile[r][chunk * 8 + j] = v[j];
    }
    __syncthreads();
    int d = t >> 2;
    #pragma unroll
    for (int it = 0; it < 2; ++it) {
        int chunk = (t & 3) + it * 4;
        ushort8v w;
        #pragma unroll
        for (int j = 0; j < 8; ++j) w[j] = tile[chunk * 8 + j][d];
        *reinterpret_cast<ushort8v*>(vt + ((size_t)(b * NKV + kh) * HD + d) * SEQ
                                        + s0 + chunk * 8) = w;
    }
}

// ---------------- causal GQA flash attention ----------------
// grid (qt=32, bh=64), 256 thr = 4 independent waves, 16 q-rows/wave.
// KVBLK=128: halves per-tile fixed softmax overhead (rescale exps, shfl
// reduces, acc-rescale) per KV element. Mask provably needed only on the
// last KV tile (non-last: max kg = kv0+127 < min qg). Scale pre-folded in Q.
// qt reversed so heavy (long-KV) tiles launch first -> shorter grid tail.
__global__ __launch_bounds__(256) void flash_attn(
    const __hip_bfloat16* __restrict__ Qp,   // [B][NH][S][HD] (pre-scaled)
    const __hip_bfloat16* __restrict__ Kp,   // [B][NKV][S][HD]
    const __hip_bfloat16* __restrict__ Vt,   // [B][NKV][HD][S]
    __hip_bfloat16* __restrict__ O) {        // [B][S][NH*HD]
    __shared__ __align__(16) __hip_bfloat16 Plds[4][16 * 128];
    const int qt   = (int)gridDim.x - 1 - (int)blockIdx.x;
    const int bh   = blockIdx.y;
    const int b    = bh >> 5, h = bh & 31;
    const int kvh  = h >> 2;
    const int wave = threadIdx.x >> 6, lane = threadIdx.x & 63;
    const int lr = lane & 15, lg = lane >> 4;
    const int qw0 = qt * 64 + wave * 16;

    const __hip_bfloat16* qbase = Qp + (((size_t)bh) * SEQ + qw0 + lr) * HD + lg * 8;
    const bf16x8 qa0 = *reinterpret_cast<const bf16x8*>(qbase);
    const bf16x8 qa1 = *reinterpret_cast<const bf16x8*>(qbase + 32);

    const __hip_bfloat16* kb = Kp + ((size_t)(b * NKV + kvh) * SEQ) * HD;
    const __hip_bfloat16* vb = Vt + ((size_t)(b * NKV + kvh) * HD) * SEQ;

    f32x4 acc[4] = {};
    float m_run[4], l_run[4];
    #pragma unroll
    for (int r = 0; r < 4; ++r) { m_run[r] = -1e30f; l_run[r] = 0.f; }

    __hip_bfloat16* pw = &Plds[wave][0];
    const int kv_end = qt * 64 + 64;

    for (int kv0 = 0; kv0 < kv_end; kv0 += 128) {
        f32x4 s[8];
        #pragma unroll
        for (int nk = 0; nk < 8; ++nk) {
            const __hip_bfloat16* kptr = kb + (size_t)(kv0 + nk * 16 + lr) * HD + lg * 8;
            bf16x8 k0 = *reinterpret_cast<const bf16x8*>(kptr);
            bf16x8 k1 = *reinterpret_cast<const bf16x8*>(kptr + 32);
            f32x4 z = {0.f, 0.f, 0.f, 0.f};
            z = __builtin_amdgcn_mfma_f32_16x16x32_bf16(qa0, k0, z, 0, 0, 0);
            z = __builtin_amdgcn_mfma_f32_16x16x32_bf16(qa1, k1, z, 0, 0, 0);
            s[nk] = z;
        }
        const bool last = (kv0 + 128 >= kv_end);
        if (last) {
            #pragma unroll
            for (int nk = 0; nk < 8; ++nk)
                #pragma unroll
                for (int r = 0; r < 4; ++r) {
                    int kg = kv0 + nk * 16 + lr;
                    int qg = qw0 + lg * 4 + r;
                    if (kg > qg) s[nk][r] = -1e30f;
                }
        }
        float tmax[4], tsum[4], alpha[4];
        #pragma unroll
        for (int r = 0; r < 4; ++r) {
            float v = s[0][r];
            #pragma unroll
            for (int nk = 1; nk < 8; ++nk) v = fmaxf(v, s[nk][r]);
            #pragma unroll
            for (int off = 1; off < 16; off <<= 1)
                v = fmaxf(v, __shfl_xor(v, off, 64));
            tmax[r] = v;
        }
        #pragma unroll
        for (int r = 0; r < 4; ++r) {
            float mn = fmaxf(m_run[r], tmax[r]);
            alpha[r] = __expf(m_run[r] - mn);
            m_run[r] = mn;
            tsum[r]  = 0.f;
        }
        #pragma unroll
        for (int nk = 0; nk < 8; ++nk)
            #pragma unroll
            for (int r = 0; r < 4; ++r) {
                float p = __expf(s[nk][r] - m_run[r]);
                tsum[r] += p;
                pw[(lg * 4 + r) * 128 + nk * 16 + lr] = __float2bfloat16(p);
            }
        #pragma unroll
        for (int r = 0; r < 4; ++r) {
            float v = tsum[r];
            #pragma unroll
            for (int off = 1; off < 16; off <<= 1)
                v += __shfl_xor(v, off, 64);
            l_run[r] = l_run[r] * alpha[r] + v;
        }
        #pragma unroll
        for (int nd = 0; nd < 4; ++nd)
            #pragma unroll
            for (int r = 0; r < 4; ++r)
                acc[nd][r] *= alpha[r];
        asm volatile("s_waitcnt lgkmcnt(0)" ::: "memory");
        bf16x8 pa[4];
        #pragma unroll
        for (int c = 0; c < 4; ++c)
            pa[c] = *reinterpret_cast<const bf16x8*>(pw + lr * 128 + c * 32 + lg * 8);
        #pragma unroll
        for (int nd = 0; nd < 4; ++nd) {
            const __hip_bfloat16* vptr = vb + (size_t)(nd * 16 + lr) * SEQ + kv0 + lg * 8;
            #pragma unroll
            for (int c = 0; c < 4; ++c) {
                bf16x8 vf = *reinterpret_cast<const bf16x8*>(vptr + c * 32);
                acc[nd] = __builtin_amdgcn_mfma_f32_16x16x32_bf16(pa[c], vf, acc[nd], 0, 0, 0);
            }
        }
    }
    #pragma unroll
    for (int nd = 0; nd < 4; ++nd)
        #pragma unroll
        for (int r = 0; r < 4; ++r) {
            int qg  = qw0 + lg * 4 + r;
            int col = h * HD + nd * 16 + lr;
            float o = acc[nd][r] / l_run[r];
            O[((size_t)(b * SEQ + qg)) * DIM + col] = __float2bfloat16(o);
        }
}

// ---------------- launch ----------------
extern "C" void kernel_launch(void* const* d_in, const int* in_sizes, int n_in,
                              void* d_out, int out_size, void* d_ws, size_t ws_size,
                              hipStream_t stream) {
    const float* x    = (const float*)d_in[0];
    const float* fcos = (const float*)d_in[1];
    const float* fsin = (const float*)d_in[2];
    const float* wq   = (const float*)d_in[3];
    const float* wk   = (const float*)d_in[4];
    const float* wv   = (const float*)d_in[5];
    const float* wo   = (const float*)d_in[6];
    float* out = (float*)d_out;

    // Workspace layout (bf16 elems). AO aliases Xb: Xb is dead after GEMM1,
    // AO is written only afterwards (flash_attn).  Total ~88 MB.
    __hip_bfloat16* Xb   = (__hip_bfloat16*)d_ws;
    __hip_bfloat16* Wqkv = Xb   + (size_t)MROWS * DIM;             // 8.39M elems
    __hip_bfloat16* Wob  = Wqkv + (size_t)QKVN * DIM;              // 6.29M
    __hip_bfloat16* QKV  = Wob  + (size_t)DIM * DIM;               // 4.19M
    __hip_bfloat16* Qp   = QKV  + (size_t)MROWS * QKVN;            // 12.58M
    __hip_bfloat16* Kp   = Qp   + (size_t)BATCH * NH * SEQ * HD;   // 8.39M
    __hip_bfloat16* Vt   = Kp   + (size_t)BATCH * NKV * SEQ * HD;  // 2.10M
    __hip_bfloat16* AO   = Xb;                                     // alias (see above)

    cvt_f32_bf16<<<(MROWS * DIM) / 1024, 256, 0, stream>>>(x, Xb, MROWS * DIM);
    cvt_f32_bf16<<<(DIM * DIM) / 1024, 256, 0, stream>>>(wq, Wqkv, DIM * DIM);
    cvt_f32_bf16<<<(NKV * HD * DIM) / 1024, 256, 0, stream>>>(wk, Wqkv + (size_t)DIM * DIM, NKV * HD * DIM);
    cvt_f32_bf16<<<(NKV * HD * DIM) / 1024, 256, 0, stream>>>(wv, Wqkv + (size_t)(DIM + NKV * HD) * DIM, NKV * HD * DIM);
    cvt_f32_bf16<<<(DIM * DIM) / 1024, 256, 0, stream>>>(wo, Wob, DIM * DIM);

    gemm_bt<__hip_bfloat16><<<dim3(MROWS / 128, QKVN / 128), 256, 0, stream>>>(
        Xb, Wqkv, QKV, MROWS, QKVN, DIM);

    rope_qk<<<(BATCH * NH * SEQ * 32) / 256, 256, 0, stream>>>(QKV, fcos, fsin, Qp, NH, 0, 0.125f);
    rope_qk<<<(BATCH * NKV * SEQ * 32) / 256, 256, 0, stream>>>(QKV, fcos, fsin, Kp, NKV, DIM, 1.0f);
    v_repack<<<BATCH * NKV * 32, 256, 0, stream>>>(QKV, Vt);

    flash_attn<<<dim3(SEQ / 64, BATCH * NH), 256, 0, stream>>>(Qp, Kp, Vt, AO);

    gemm_bt<float><<<dim3(MROWS / 128, DIM / 128), 256, 0, stream>>>(
        AO, Wob, out, MROWS, DIM, DIM);
}

// Round 5
// 704.233 us; speedup vs baseline: 1.0019x; 1.0019x over previous
//
#include <hip/hip_runtime.h>
#include <hip/hip_bf16.h>
#include <stdint.h>

#define BATCH 2
#define SEQ   2048
#define DIM   2048
#define NH    32
#define NKV   8
#define HD    64
#define QKVN  3072   // DIM + 2*NKV*HD
#define MROWS 4096   // BATCH*SEQ

typedef __bf16 bf16x8 __attribute__((ext_vector_type(8)));
typedef float  f32x4  __attribute__((ext_vector_type(4)));
typedef unsigned short ushort8v __attribute__((ext_vector_type(8)));

typedef __attribute__((address_space(3))) void lds_void;
typedef const __attribute__((address_space(1))) void gbl_void;

__device__ __forceinline__ void gload_lds16(const void* g, void* l) {
    __builtin_amdgcn_global_load_lds((gbl_void*)g, (lds_void*)l, 16, 0, 0);
}

// ---------------- fp32 -> bf16 convert (vectorized) ----------------
__global__ void cvt_f32_bf16(const float* __restrict__ in,
                             __hip_bfloat16* __restrict__ out, int n) {
    int i = (blockIdx.x * 256 + threadIdx.x) * 4;
    if (i >= n) return;
    const float4 v = *reinterpret_cast<const float4*>(in + i);
    union { ushort4 u; __hip_bfloat16 h[4]; } o;
    o.h[0] = __float2bfloat16(v.x);
    o.h[1] = __float2bfloat16(v.y);
    o.h[2] = __float2bfloat16(v.z);
    o.h[3] = __float2bfloat16(v.w);
    *reinterpret_cast<ushort4*>(out + i) = o.u;
}

// ---------------- GEMM: C[M,N] = A[M,K] * B[N,K]^T  (m97 structure) -----
__device__ __forceinline__ void store_out(float* p, float v) { *p = v; }
__device__ __forceinline__ void store_out(__hip_bfloat16* p, float v) { *p = __float2bfloat16(v); }

template <typename OUT_T>
__global__ __launch_bounds__(256) void gemm_bt(
    const __hip_bfloat16* __restrict__ A,
    const __hip_bfloat16* __restrict__ B,
    OUT_T* __restrict__ C,
    int M, int N, int K)
{
    __shared__ __align__(16) __hip_bfloat16 As[128 * 32];
    __shared__ __align__(16) __hip_bfloat16 Bs[128 * 32];
    const int tid  = threadIdx.x;
    const int lane = tid & 63;
    const int wave = tid >> 6;
    const int wr = wave >> 1, wc = wave & 1;
    const int lr = lane & 15, lg = lane >> 4;
    const size_t tm = (size_t)blockIdx.x * 128;
    const size_t tn = (size_t)blockIdx.y * 128;

    f32x4 acc[4][4] = {};

    const int srow  = tid >> 2;        // 0..63
    const int scol  = (tid & 3) * 8;   // elem offset in K-step
    const int wbase = wave * 512;      // elems (1024B per wave chunk)

    const __hip_bfloat16* pa = As + (wr * 64 + lr) * 32 + lg * 8;
    const __hip_bfloat16* pb = Bs + (wc * 64 + lr) * 32 + lg * 8;

    for (int k0 = 0; k0 < K; k0 += 32) {
        const __hip_bfloat16* gA = A + (tm + srow) * (size_t)K + k0 + scol;
        const __hip_bfloat16* gB = B + (tn + srow) * (size_t)K + k0 + scol;
        gload_lds16(gA,                 (void*)(As + wbase));
        gload_lds16(gA + (size_t)64*K,  (void*)(As + 2048 + wbase));
        gload_lds16(gB,                 (void*)(Bs + wbase));
        gload_lds16(gB + (size_t)64*K,  (void*)(Bs + 2048 + wbase));
        __syncthreads();   // compiler drains vmcnt before s_barrier
        bf16x8 af[4], bfr[4];
        #pragma unroll
        for (int m = 0; m < 4; ++m) af[m]  = *reinterpret_cast<const bf16x8*>(pa + m * 512);
        #pragma unroll
        for (int n = 0; n < 4; ++n) bfr[n] = *reinterpret_cast<const bf16x8*>(pb + n * 512);
        #pragma unroll
        for (int m = 0; m < 4; ++m)
            #pragma unroll
            for (int n = 0; n < 4; ++n)
                acc[m][n] = __builtin_amdgcn_mfma_f32_16x16x32_bf16(af[m], bfr[n], acc[m][n], 0, 0, 0);
        __syncthreads();
    }

    #pragma unroll
    for (int m = 0; m < 4; ++m)
        #pragma unroll
        for (int n = 0; n < 4; ++n)
            #pragma unroll
            for (int r = 0; r < 4; ++r) {
                size_t row = tm + wr * 64 + m * 16 + lg * 4 + r;
                size_t col = tn + wc * 64 + n * 16 + lr;
                store_out(&C[row * (size_t)N + col], acc[m][n][r]);
            }
}

// ---------------- RoPE (interleaved pairs) + repack ----------------
// mul: extra scale folded into the rotated output (Q gets 1/sqrt(HD)=0.125,
// an exact power of two -> no added bf16 rounding error; K gets 1.0).
__global__ void rope_qk(const __hip_bfloat16* __restrict__ qkv,
                        const float* __restrict__ fcos,
                        const float* __restrict__ fsin,
                        __hip_bfloat16* __restrict__ outp,
                        int nheads, int col_off, float mul) {
    int idx = blockIdx.x * 256 + threadIdx.x;
    int i  = idx & 31;
    int s  = (idx >> 5) & (SEQ - 1);
    int bh = idx >> 16;             // SEQ*32 = 65536
    int h  = bh % nheads;
    const __hip_bfloat16* src = qkv + ((size_t)(bh / nheads) * SEQ + s) * QKVN
                                    + col_off + h * HD + 2 * i;
    union { unsigned int u; __hip_bfloat16 h2[2]; } in_, out_;
    in_.u = *reinterpret_cast<const unsigned int*>(src);
    float t0 = __bfloat162float(in_.h2[0]);
    float t1 = __bfloat162float(in_.h2[1]);
    float c  = fcos[s * 32 + i] * mul;
    float sn = fsin[s * 32 + i] * mul;
    out_.h2[0] = __float2bfloat16(t0 * c - t1 * sn);
    out_.h2[1] = __float2bfloat16(t0 * sn + t1 * c);
    *reinterpret_cast<unsigned int*>(outp + ((size_t)bh * SEQ + s) * HD + 2 * i) = out_.u;
}

// V: [b][s][2560 + kh*64 + d] -> Vt[b][kh][d][s]  (LDS tile transpose)
__global__ __launch_bounds__(256) void v_repack(const __hip_bfloat16* __restrict__ qkv,
                                                __hip_bfloat16* __restrict__ vt) {
    __shared__ unsigned short tile[64][66];
    int blk = blockIdx.x;              // 2*8*32 = 512
    int st = blk & 31;
    int kh = (blk >> 5) & 7;
    int b  = blk >> 8;
    int s0 = st * 64;
    int t  = threadIdx.x;
    int r  = t >> 2;
    #pragma unroll
    for (int it = 0; it < 2; ++it) {
        int chunk = (t & 3) + it * 4;   // 0..7
        const __hip_bfloat16* src = qkv + ((size_t)(b * SEQ + s0 + r)) * QKVN
                                        + 2560 + kh * HD + chunk * 8;
        ushort8v v = *reinterpret_cast<const ushort8v*>(src);
        #pragma unroll
        for (int j = 0; j < 8; ++j) tile[r][chunk * 8 + j] = v[j];
    }
    __syncthreads();
    int d = t >> 2;
    #pragma unroll
    for (int it = 0; it < 2; ++it) {
        int chunk = (t & 3) + it * 4;
        ushort8v w;
        #pragma unroll
        for (int j = 0; j < 8; ++j) w[j] = tile[chunk * 8 + j][d];
        *reinterpret_cast<ushort8v*>(vt + ((size_t)(b * NKV + kh) * HD + d) * SEQ
                                        + s0 + chunk * 8) = w;
    }
}

__device__ __forceinline__ unsigned pack_bf16x2(float lo, float hi) {
    __hip_bfloat162 t;
    t.x = __float2bfloat16(lo);
    t.y = __float2bfloat16(hi);
    return *reinterpret_cast<unsigned*>(&t);
}

// ---------------- causal GQA flash attention (swapped QK^T) ----------------
// grid (qt=32, bh=64), 4 waves/block, 16 q-rows/wave, KVBLK=64.
// mfma(A=K, B=Q): lane (lr,lg) holds S[q=qw0+lr][k=kv0+nk*16+lg*4+r]
// -> softmax row is lane-local: in-lane tree + 2 shfl hops (xor 16, 32).
// P packed as b64 writes to XOR-swizzled LDS, re-read as PV A-frags.
// __launch_bounds__(256,4): pin 128-VGPR bin (round-3 showed 64-VGPR spill).
__global__ __launch_bounds__(256, 4) void flash_attn(
    const __hip_bfloat16* __restrict__ Qp,   // [B][NH][S][HD] (pre-scaled by 0.125)
    const __hip_bfloat16* __restrict__ Kp,   // [B][NKV][S][HD]
    const __hip_bfloat16* __restrict__ Vt,   // [B][NKV][HD][S]
    __hip_bfloat16* __restrict__ O) {        // [B][S][NH*HD]
    __shared__ __align__(16) unsigned char Plds[4][16 * 128];  // per wave: 16 q x 64 k bf16
    const int qt   = (int)gridDim.x - 1 - (int)blockIdx.x;
    const int bh   = blockIdx.y;
    const int b    = bh >> 5, h = bh & 31;
    const int kvh  = h >> 2;
    const int wave = threadIdx.x >> 6, lane = threadIdx.x & 63;
    const int lr = lane & 15, lg = lane >> 4;
    const int qw0 = qt * 64 + wave * 16;

    // Q as B-operand fragments (B-frag "row" = output col = q-row qw0+lr)
    const __hip_bfloat16* qbase = Qp + (((size_t)bh) * SEQ + qw0 + lr) * HD + lg * 8;
    const bf16x8 qa0 = *reinterpret_cast<const bf16x8*>(qbase);
    const bf16x8 qa1 = *reinterpret_cast<const bf16x8*>(qbase + 32);

    const __hip_bfloat16* kb = Kp + ((size_t)(b * NKV + kvh) * SEQ) * HD;
    const __hip_bfloat16* vb = Vt + ((size_t)(b * NKV + kvh) * HD) * SEQ;

    f32x4 acc[4] = {};          // O[q=qw0+lg*4+r][d=nd*16+lr]
    float m_run = -1e30f, l_run = 0.f;   // per-lane state for q = qw0+lr

    unsigned char* pw = &Plds[wave][0];
    const int swz = (lr & 7) << 4;
    const int kv_end = qt * 64 + 64;

    for (int kv0 = 0; kv0 < kv_end; kv0 += 64) {
        // S^T tile: s[nk][r] = S[q=qw0+lr][k=kv0+nk*16+lg*4+r]
        f32x4 s[4];
        #pragma unroll
        for (int nk = 0; nk < 4; ++nk) {
            const __hip_bfloat16* kptr = kb + (size_t)(kv0 + nk * 16 + lr) * HD + lg * 8;
            bf16x8 k0 = *reinterpret_cast<const bf16x8*>(kptr);
            bf16x8 k1 = *reinterpret_cast<const bf16x8*>(kptr + 32);
            f32x4 z = {0.f, 0.f, 0.f, 0.f};
            z = __builtin_amdgcn_mfma_f32_16x16x32_bf16(k0, qa0, z, 0, 0, 0);
            z = __builtin_amdgcn_mfma_f32_16x16x32_bf16(k1, qa1, z, 0, 0, 0);
            s[nk] = z;
        }
        if (kv0 + 64 >= kv_end) {   // last tile only (earlier tiles provably unmasked)
            const int qg = qw0 + lr;
            #pragma unroll
            for (int nk = 0; nk < 4; ++nk) {
                const int kbase = kv0 + nk * 16 + lg * 4;
                #pragma unroll
                for (int r = 0; r < 4; ++r)
                    if (kbase + r > qg) s[nk][r] = -1e30f;
            }
        }
        // row max: in-lane tree over 16, then 2 cross-lane hops
        float tmax = fmaxf(fmaxf(s[0][0], s[0][1]), fmaxf(s[0][2], s[0][3]));
        #pragma unroll
        for (int nk = 1; nk < 4; ++nk)
            tmax = fmaxf(tmax, fmaxf(fmaxf(s[nk][0], s[nk][1]), fmaxf(s[nk][2], s[nk][3])));
        tmax = fmaxf(tmax, __shfl_xor(tmax, 16, 64));
        tmax = fmaxf(tmax, __shfl_xor(tmax, 32, 64));
        const float mn    = fmaxf(m_run, tmax);
        const float alpha = __expf(m_run - mn);
        m_run = mn;
        // p = exp(s - m), pack bf16 pairs, swizzled b64 write, in-lane sum
        float tsum = 0.f;
        #pragma unroll
        for (int nk = 0; nk < 4; ++nk) {
            float p0 = __expf(s[nk][0] - m_run);
            float p1 = __expf(s[nk][1] - m_run);
            float p2 = __expf(s[nk][2] - m_run);
            float p3 = __expf(s[nk][3] - m_run);
            tsum += (p0 + p1) + (p2 + p3);
            uint2 pk;
            pk.x = pack_bf16x2(p0, p1);
            pk.y = pack_bf16x2(p2, p3);
            *reinterpret_cast<uint2*>(pw + lr * 128 + ((nk * 32 + lg * 8) ^ swz)) = pk;
        }
        tsum += __shfl_xor(tsum, 16, 64);
        tsum += __shfl_xor(tsum, 32, 64);
        l_run = l_run * alpha + tsum;
        // rescale acc: alpha of q-row (lg*4+r) lives at lane (lg*4+r)
        float a0 = __shfl(alpha, lg * 4 + 0, 64);
        float a1 = __shfl(alpha, lg * 4 + 1, 64);
        float a2 = __shfl(alpha, lg * 4 + 2, 64);
        float a3 = __shfl(alpha, lg * 4 + 3, 64);
        #pragma unroll
        for (int nd = 0; nd < 4; ++nd) {
            acc[nd][0] *= a0; acc[nd][1] *= a1;
            acc[nd][2] *= a2; acc[nd][3] *= a3;
        }
        asm volatile("s_waitcnt lgkmcnt(0)" ::: "memory");
        __builtin_amdgcn_sched_barrier(0);
        // PV A-frags: P[q=lr][k = c*32 + lg*8 .. +7] (swizzle-matched 16B reads)
        const bf16x8 pa0 = *reinterpret_cast<const bf16x8*>(pw + lr * 128 + ((     lg * 16) ^ swz));
        const bf16x8 pa1 = *reinterpret_cast<const bf16x8*>(pw + lr * 128 + ((64 + lg * 16) ^ swz));
        #pragma unroll
        for (int nd = 0; nd < 4; ++nd) {
            const __hip_bfloat16* vptr = vb + (size_t)(nd * 16 + lr) * SEQ + kv0 + lg * 8;
            bf16x8 v0 = *reinterpret_cast<const bf16x8*>(vptr);
            bf16x8 v1 = *reinterpret_cast<const bf16x8*>(vptr + 32);
            acc[nd] = __builtin_amdgcn_mfma_f32_16x16x32_bf16(pa0, v0, acc[nd], 0, 0, 0);
            acc[nd] = __builtin_amdgcn_mfma_f32_16x16x32_bf16(pa1, v1, acc[nd], 0, 0, 0);
        }
    }
    // epilogue: l for q-row (lg*4+r) lives at lane (lg*4+r)
    float linv[4];
    #pragma unroll
    for (int r = 0; r < 4; ++r)
        linv[r] = 1.f / __shfl(l_run, lg * 4 + r, 64);
    #pragma unroll
    for (int nd = 0; nd < 4; ++nd)
        #pragma unroll
        for (int r = 0; r < 4; ++r) {
            int qg  = qw0 + lg * 4 + r;
            int col = h * HD + nd * 16 + lr;
            O[((size_t)(b * SEQ + qg)) * DIM + col] = __float2bfloat16(acc[nd][r] * linv[r]);
        }
}

// ---------------- launch ----------------
extern "C" void kernel_launch(void* const* d_in, const int* in_sizes, int n_in,
                              void* d_out, int out_size, void* d_ws, size_t ws_size,
                              hipStream_t stream) {
    const float* x    = (const float*)d_in[0];
    const float* fcos = (const float*)d_in[1];
    const float* fsin = (const float*)d_in[2];
    const float* wq   = (const float*)d_in[3];
    const float* wk   = (const float*)d_in[4];
    const float* wv   = (const float*)d_in[5];
    const float* wo   = (const float*)d_in[6];
    float* out = (float*)d_out;

    // Workspace layout (bf16 elems). AO aliases Xb: Xb dead after GEMM1.
    __hip_bfloat16* Xb   = (__hip_bfloat16*)d_ws;
    __hip_bfloat16* Wqkv = Xb   + (size_t)MROWS * DIM;
    __hip_bfloat16* Wob  = Wqkv + (size_t)QKVN * DIM;
    __hip_bfloat16* QKV  = Wob  + (size_t)DIM * DIM;
    __hip_bfloat16* Qp   = QKV  + (size_t)MROWS * QKVN;
    __hip_bfloat16* Kp   = Qp   + (size_t)BATCH * NH * SEQ * HD;
    __hip_bfloat16* Vt   = Kp   + (size_t)BATCH * NKV * SEQ * HD;
    __hip_bfloat16* AO   = Xb;                                  // alias

    cvt_f32_bf16<<<(MROWS * DIM) / 1024, 256, 0, stream>>>(x, Xb, MROWS * DIM);
    cvt_f32_bf16<<<(DIM * DIM) / 1024, 256, 0, stream>>>(wq, Wqkv, DIM * DIM);
    cvt_f32_bf16<<<(NKV * HD * DIM) / 1024, 256, 0, stream>>>(wk, Wqkv + (size_t)DIM * DIM, NKV * HD * DIM);
    cvt_f32_bf16<<<(NKV * HD * DIM) / 1024, 256, 0, stream>>>(wv, Wqkv + (size_t)(DIM + NKV * HD) * DIM, NKV * HD * DIM);
    cvt_f32_bf16<<<(DIM * DIM) / 1024, 256, 0, stream>>>(wo, Wob, DIM * DIM);

    gemm_bt<__hip_bfloat16><<<dim3(MROWS / 128, QKVN / 128), 256, 0, stream>>>(
        Xb, Wqkv, QKV, MROWS, QKVN, DIM);

    rope_qk<<<(BATCH * NH * SEQ * 32) / 256, 256, 0, stream>>>(QKV, fcos, fsin, Qp, NH, 0, 0.125f);
    rope_qk<<<(BATCH * NKV * SEQ * 32) / 256, 256, 0, stream>>>(QKV, fcos, fsin, Kp, NKV, DIM, 1.0f);
    v_repack<<<BATCH * NKV * 32, 256, 0, stream>>>(QKV, Vt);

    flash_attn<<<dim3(SEQ / 64, BATCH * NH), 256, 0, stream>>>(Qp, Kp, Vt, AO);

    gemm_bt<float><<<dim3(MROWS / 128, DIM / 128), 256, 0, stream>>>(
        AO, Wob, out, MROWS, DIM, DIM);
}

// Round 7
// 386.566 us; speedup vs baseline: 1.8252x; 1.8218x over previous
//
#include <hip/hip_runtime.h>
#include <hip/hip_bf16.h>
#include <stdint.h>

#define BATCH 2
#define SEQ   2048
#define DIM   2048
#define NH    32
#define NKV   8
#define HD    64
#define QKVN  3072   // DIM + 2*NKV*HD
#define MROWS 4096   // BATCH*SEQ

typedef __bf16 bf16x8 __attribute__((ext_vector_type(8)));
typedef float  f32x4  __attribute__((ext_vector_type(4)));
typedef unsigned short ushort8v __attribute__((ext_vector_type(8)));

typedef __attribute__((address_space(3))) void lds_void;
typedef const __attribute__((address_space(1))) void gbl_void;

__device__ __forceinline__ void gload_lds16(const void* g, void* l) {
    __builtin_amdgcn_global_load_lds((gbl_void*)g, (lds_void*)l, 16, 0, 0);
}

// ---------------- fp32 -> bf16 convert (vectorized) ----------------
__global__ void cvt_f32_bf16(const float* __restrict__ in,
                             __hip_bfloat16* __restrict__ out, int n) {
    int i = (blockIdx.x * 256 + threadIdx.x) * 4;
    if (i >= n) return;
    const float4 v = *reinterpret_cast<const float4*>(in + i);
    union { ushort4 u; __hip_bfloat16 h[4]; } o;
    o.h[0] = __float2bfloat16(v.x);
    o.h[1] = __float2bfloat16(v.y);
    o.h[2] = __float2bfloat16(v.z);
    o.h[3] = __float2bfloat16(v.w);
    *reinterpret_cast<ushort4*>(out + i) = o.u;
}

// ---------------- GEMM: C[M,N] = A[M,K] * B[N,K]^T  (m97 structure) -----
__device__ __forceinline__ void store_out(float* p, float v) { *p = v; }
__device__ __forceinline__ void store_out(__hip_bfloat16* p, float v) { *p = __float2bfloat16(v); }

template <typename OUT_T>
__global__ __launch_bounds__(256) void gemm_bt(
    const __hip_bfloat16* __restrict__ A,
    const __hip_bfloat16* __restrict__ B,
    OUT_T* __restrict__ C,
    int M, int N, int K)
{
    __shared__ __align__(16) __hip_bfloat16 As[128 * 32];
    __shared__ __align__(16) __hip_bfloat16 Bs[128 * 32];
    const int tid  = threadIdx.x;
    const int lane = tid & 63;
    const int wave = tid >> 6;
    const int wr = wave >> 1, wc = wave & 1;
    const int lr = lane & 15, lg = lane >> 4;
    const size_t tm = (size_t)blockIdx.x * 128;
    const size_t tn = (size_t)blockIdx.y * 128;

    f32x4 acc[4][4] = {};

    const int srow  = tid >> 2;        // 0..63
    const int scol  = (tid & 3) * 8;   // elem offset in K-step
    const int wbase = wave * 512;      // elems (1024B per wave chunk)

    const __hip_bfloat16* pa = As + (wr * 64 + lr) * 32 + lg * 8;
    const __hip_bfloat16* pb = Bs + (wc * 64 + lr) * 32 + lg * 8;

    for (int k0 = 0; k0 < K; k0 += 32) {
        const __hip_bfloat16* gA = A + (tm + srow) * (size_t)K + k0 + scol;
        const __hip_bfloat16* gB = B + (tn + srow) * (size_t)K + k0 + scol;
        gload_lds16(gA,                 (void*)(As + wbase));
        gload_lds16(gA + (size_t)64*K,  (void*)(As + 2048 + wbase));
        gload_lds16(gB,                 (void*)(Bs + wbase));
        gload_lds16(gB + (size_t)64*K,  (void*)(Bs + 2048 + wbase));
        __syncthreads();   // compiler drains vmcnt before s_barrier
        bf16x8 af[4], bfr[4];
        #pragma unroll
        for (int m = 0; m < 4; ++m) af[m]  = *reinterpret_cast<const bf16x8*>(pa + m * 512);
        #pragma unroll
        for (int n = 0; n < 4; ++n) bfr[n] = *reinterpret_cast<const bf16x8*>(pb + n * 512);
        #pragma unroll
        for (int m = 0; m < 4; ++m)
            #pragma unroll
            for (int n = 0; n < 4; ++n)
                acc[m][n] = __builtin_amdgcn_mfma_f32_16x16x32_bf16(af[m], bfr[n], acc[m][n], 0, 0, 0);
        __syncthreads();
    }

    #pragma unroll
    for (int m = 0; m < 4; ++m)
        #pragma unroll
        for (int n = 0; n < 4; ++n)
            #pragma unroll
            for (int r = 0; r < 4; ++r) {
                size_t row = tm + wr * 64 + m * 16 + lg * 4 + r;
                size_t col = tn + wc * 64 + n * 16 + lr;
                store_out(&C[row * (size_t)N + col], acc[m][n][r]);
            }
}

// ---------------- RoPE (interleaved pairs) + repack ----------------
__global__ void rope_qk(const __hip_bfloat16* __restrict__ qkv,
                        const float* __restrict__ fcos,
                        const float* __restrict__ fsin,
                        __hip_bfloat16* __restrict__ outp,
                        int nheads, int col_off, float mul) {
    int idx = blockIdx.x * 256 + threadIdx.x;
    int i  = idx & 31;
    int s  = (idx >> 5) & (SEQ - 1);
    int bh = idx >> 16;             // SEQ*32 = 65536
    int h  = bh % nheads;
    const __hip_bfloat16* src = qkv + ((size_t)(bh / nheads) * SEQ + s) * QKVN
                                    + col_off + h * HD + 2 * i;
    union { unsigned int u; __hip_bfloat16 h2[2]; } in_, out_;
    in_.u = *reinterpret_cast<const unsigned int*>(src);
    float t0 = __bfloat162float(in_.h2[0]);
    float t1 = __bfloat162float(in_.h2[1]);
    float c  = fcos[s * 32 + i] * mul;
    float sn = fsin[s * 32 + i] * mul;
    out_.h2[0] = __float2bfloat16(t0 * c - t1 * sn);
    out_.h2[1] = __float2bfloat16(t0 * sn + t1 * c);
    *reinterpret_cast<unsigned int*>(outp + ((size_t)bh * SEQ + s) * HD + 2 * i) = out_.u;
}

// V: [b][s][2560 + kh*64 + d] -> Vt[b][kh][d][s]  (LDS tile transpose)
__global__ __launch_bounds__(256) void v_repack(const __hip_bfloat16* __restrict__ qkv,
                                                __hip_bfloat16* __restrict__ vt) {
    __shared__ unsigned short tile[64][66];
    int blk = blockIdx.x;              // 2*8*32 = 512
    int st = blk & 31;
    int kh = (blk >> 5) & 7;
    int b  = blk >> 8;
    int s0 = st * 64;
    int t  = threadIdx.x;
    int r  = t >> 2;
    #pragma unroll
    for (int it = 0; it < 2; ++it) {
        int chunk = (t & 3) + it * 4;   // 0..7
        const __hip_bfloat16* src = qkv + ((size_t)(b * SEQ + s0 + r)) * QKVN
                                        + 2560 + kh * HD + chunk * 8;
        ushort8v v = *reinterpret_cast<const ushort8v*>(src);
        #pragma unroll
        for (int j = 0; j < 8; ++j) tile[r][chunk * 8 + j] = v[j];
    }
    __syncthreads();
    int d = t >> 2;
    #pragma unroll
    for (int it = 0; it < 2; ++it) {
        int chunk = (t & 3) + it * 4;
        ushort8v w;
        #pragma unroll
        for (int j = 0; j < 8; ++j) w[j] = tile[chunk * 8 + j][d];
        *reinterpret_cast<ushort8v*>(vt + ((size_t)(b * NKV + kh) * HD + d) * SEQ
                                        + s0 + chunk * 8) = w;
    }
}

__device__ __forceinline__ unsigned pack_bf16x2(float lo, float hi) {
    __hip_bfloat162 t;
    t.x = __float2bfloat16(lo);
    t.y = __float2bfloat16(hi);
    return *reinterpret_cast<unsigned*>(&t);
}

// ---------------- causal GQA flash attention (LDS-staged K/V) ----------------
// Round-5 A/B showed dur invariant under full inner-loop rewrite => bottleneck
// was the strided multi-line global K/V loads (16 lines/instr, 4x redundant
// across waves; ~34.6M line-fills ~ MSHR-limited ~1.05M cyc/CU = 440us).
// Fix: stage K-tile (64x64) and V-tile (64x64) in LDS via 4 coalesced
// global_load_lds width=16 per block-tile (8 lanes = one full 128B line),
// XOR-pre-swizzled source (rule #21) so swizzled ds_read_b128 frags spread
// 2 lanes/bank-group (optimal). Double-buffered, 1 barrier/tile.
__global__ __launch_bounds__(256, 4) void flash_attn(
    const __hip_bfloat16* __restrict__ Qp,   // [B][NH][S][HD] (pre-scaled by 0.125)
    const __hip_bfloat16* __restrict__ Kp,   // [B][NKV][S][HD]
    const __hip_bfloat16* __restrict__ Vt,   // [B][NKV][HD][S]
    __hip_bfloat16* __restrict__ O) {        // [B][S][NH*HD]
    __shared__ __align__(16) __hip_bfloat16 Kst[2][4096];   // 2 x 8KB
    __shared__ __align__(16) __hip_bfloat16 Vst[2][4096];   // 2 x 8KB
    __shared__ __align__(16) unsigned char Plds[4][2048];   // per-wave P
    const int qt   = (int)gridDim.x - 1 - (int)blockIdx.x;
    const int bh   = blockIdx.y;
    const int b    = bh >> 5, h = bh & 31;
    const int kvh  = h >> 2;
    const int tid  = threadIdx.x;
    const int wave = tid >> 6, lane = tid & 63;
    const int lr = lane & 15, lg = lane >> 4;
    const int qw0 = qt * 64 + wave * 16;

    // Q as B-operand fragments
    const __hip_bfloat16* qbase = Qp + (((size_t)bh) * SEQ + qw0 + lr) * HD + lg * 8;
    const bf16x8 qa0 = *reinterpret_cast<const bf16x8*>(qbase);
    const bf16x8 qa1 = *reinterpret_cast<const bf16x8*>(qbase + 32);

    const __hip_bfloat16* kb = Kp + ((size_t)(b * NKV + kvh) * SEQ) * HD;
    const __hip_bfloat16* vb = Vt + ((size_t)(b * NKV + kvh) * HD) * SEQ;

    // ---- staging geometry (per thread) ----
    // rows within a 32-row issue group; chunk pre-swizzled so LDS[row][slot]
    // holds global chunk slot^(row&7)  (involution, matched on read)
    const int srow = tid >> 3;                 // 0..31
    const int sch  = (tid & 7) ^ (srow & 7);   // permuted 16B chunk within row
    const size_t koff0 = (size_t)srow        * HD  + sch * 8;
    const size_t koff1 = (size_t)(srow + 32) * HD  + sch * 8;
    const size_t voff0 = (size_t)srow        * SEQ + sch * 8;
    const size_t voff1 = (size_t)(srow + 32) * SEQ + sch * 8;
    const int wvb = wave * 1024;               // LDS byte base per wave issue

    // ---- fragment ds_read offsets (elems), kv0-invariant ----
    // row = g*16+lr (row&7 = lr&7); half c covers elems c*32 + lg*8
    int foff[4][2];
    #pragma unroll
    for (int g = 0; g < 4; ++g)
        #pragma unroll
        for (int c = 0; c < 2; ++c)
            foff[g][c] = (g * 16 + lr) * 64 + (((c * 4 + lg) ^ (lr & 7)) * 8);

    f32x4 acc[4] = {};          // O[q=qw0+lg*4+r][d=nd*16+lr]
    float m_run = -1e30f, l_run = 0.f;   // per-lane state for q = qw0+lr

    unsigned char* pw = &Plds[wave][0];
    const int swz = (lr & 7) << 4;
    const int kv_end = qt * 64 + 64;

    // prologue: stage first tile into buf 0
    {
        char* kd = (char*)&Kst[0][0];
        char* vd = (char*)&Vst[0][0];
        gload_lds16(kb + koff0, kd + wvb);
        gload_lds16(kb + koff1, kd + 4096 + wvb);
        gload_lds16(vb + voff0, vd + wvb);
        gload_lds16(vb + voff1, vd + 4096 + wvb);
    }
    int cur = 0;

    for (int kv0 = 0; kv0 < kv_end; kv0 += 64) {
        __syncthreads();    // drains staging of buf[cur]
        if (kv0 + 64 < kv_end) {   // prefetch next tile into buf[cur^1]
            const __hip_bfloat16* ks = kb + (size_t)(kv0 + 64) * HD;
            const __hip_bfloat16* vs = vb + (kv0 + 64);
            char* kd = (char*)&Kst[cur ^ 1][0];
            char* vd = (char*)&Vst[cur ^ 1][0];
            gload_lds16(ks + koff0, kd + wvb);
            gload_lds16(ks + koff1, kd + 4096 + wvb);
            gload_lds16(vs + voff0, vd + wvb);
            gload_lds16(vs + voff1, vd + 4096 + wvb);
        }
        const __hip_bfloat16* Kl = &Kst[cur][0];
        const __hip_bfloat16* Vl = &Vst[cur][0];

        // S^T tile: s[nk][r] = S[q=qw0+lr][k=kv0+nk*16+lg*4+r]
        f32x4 s[4];
        #pragma unroll
        for (int nk = 0; nk < 4; ++nk) {
            bf16x8 k0 = *reinterpret_cast<const bf16x8*>(Kl + foff[nk][0]);
            bf16x8 k1 = *reinterpret_cast<const bf16x8*>(Kl + foff[nk][1]);
            f32x4 z = {0.f, 0.f, 0.f, 0.f};
            z = __builtin_amdgcn_mfma_f32_16x16x32_bf16(k0, qa0, z, 0, 0, 0);
            z = __builtin_amdgcn_mfma_f32_16x16x32_bf16(k1, qa1, z, 0, 0, 0);
            s[nk] = z;
        }
        if (kv0 + 64 >= kv_end) {   // last tile only (earlier tiles provably unmasked)
            const int qg = qw0 + lr;
            #pragma unroll
            for (int nk = 0; nk < 4; ++nk) {
                const int kbase = kv0 + nk * 16 + lg * 4;
                #pragma unroll
                for (int r = 0; r < 4; ++r)
                    if (kbase + r > qg) s[nk][r] = -1e30f;
            }
        }
        // row max: in-lane tree over 16, then 2 cross-lane hops
        float tmax = fmaxf(fmaxf(s[0][0], s[0][1]), fmaxf(s[0][2], s[0][3]));
        #pragma unroll
        for (int nk = 1; nk < 4; ++nk)
            tmax = fmaxf(tmax, fmaxf(fmaxf(s[nk][0], s[nk][1]), fmaxf(s[nk][2], s[nk][3])));
        tmax = fmaxf(tmax, __shfl_xor(tmax, 16, 64));
        tmax = fmaxf(tmax, __shfl_xor(tmax, 32, 64));
        const float mn    = fmaxf(m_run, tmax);
        const float alpha = __expf(m_run - mn);
        m_run = mn;
        // p = exp(s - m), pack bf16 pairs, swizzled b64 write, in-lane sum
        float tsum = 0.f;
        #pragma unroll
        for (int nk = 0; nk < 4; ++nk) {
            float p0 = __expf(s[nk][0] - m_run);
            float p1 = __expf(s[nk][1] - m_run);
            float p2 = __expf(s[nk][2] - m_run);
            float p3 = __expf(s[nk][3] - m_run);
            tsum += (p0 + p1) + (p2 + p3);
            uint2 pk;
            pk.x = pack_bf16x2(p0, p1);
            pk.y = pack_bf16x2(p2, p3);
            *reinterpret_cast<uint2*>(pw + lr * 128 + ((nk * 32 + lg * 8) ^ swz)) = pk;
        }
        tsum += __shfl_xor(tsum, 16, 64);
        tsum += __shfl_xor(tsum, 32, 64);
        l_run = l_run * alpha + tsum;
        // rescale acc: alpha of q-row (lg*4+r) lives at lane (lg*4+r)
        float a0 = __shfl(alpha, lg * 4 + 0, 64);
        float a1 = __shfl(alpha, lg * 4 + 1, 64);
        float a2 = __shfl(alpha, lg * 4 + 2, 64);
        float a3 = __shfl(alpha, lg * 4 + 3, 64);
        #pragma unroll
        for (int nd = 0; nd < 4; ++nd) {
            acc[nd][0] *= a0; acc[nd][1] *= a1;
            acc[nd][2] *= a2; acc[nd][3] *= a3;
        }
        asm volatile("s_waitcnt lgkmcnt(0)" ::: "memory");
        __builtin_amdgcn_sched_barrier(0);
        // PV A-frags: P[q=lr][k = c*32 + lg*8 .. +7] (swizzle-matched 16B reads)
        const bf16x8 pa0 = *reinterpret_cast<const bf16x8*>(pw + lr * 128 + ((     lg * 16) ^ swz));
        const bf16x8 pa1 = *reinterpret_cast<const bf16x8*>(pw + lr * 128 + ((64 + lg * 16) ^ swz));
        #pragma unroll
        for (int nd = 0; nd < 4; ++nd) {
            bf16x8 v0 = *reinterpret_cast<const bf16x8*>(Vl + foff[nd][0]);
            bf16x8 v1 = *reinterpret_cast<const bf16x8*>(Vl + foff[nd][1]);
            acc[nd] = __builtin_amdgcn_mfma_f32_16x16x32_bf16(pa0, v0, acc[nd], 0, 0, 0);
            acc[nd] = __builtin_amdgcn_mfma_f32_16x16x32_bf16(pa1, v1, acc[nd], 0, 0, 0);
        }
        cur ^= 1;
    }
    // epilogue: l for q-row (lg*4+r) lives at lane (lg*4+r)
    float linv[4];
    #pragma unroll
    for (int r = 0; r < 4; ++r)
        linv[r] = 1.f / __shfl(l_run, lg * 4 + r, 64);
    #pragma unroll
    for (int nd = 0; nd < 4; ++nd)
        #pragma unroll
        for (int r = 0; r < 4; ++r) {
            int qg  = qw0 + lg * 4 + r;
            int col = h * HD + nd * 16 + lr;
            O[((size_t)(b * SEQ + qg)) * DIM + col] = __float2bfloat16(acc[nd][r] * linv[r]);
        }
}

// ---------------- launch ----------------
extern "C" void kernel_launch(void* const* d_in, const int* in_sizes, int n_in,
                              void* d_out, int out_size, void* d_ws, size_t ws_size,
                              hipStream_t stream) {
    const float* x    = (const float*)d_in[0];
    const float* fcos = (const float*)d_in[1];
    const float* fsin = (const float*)d_in[2];
    const float* wq   = (const float*)d_in[3];
    const float* wk   = (const float*)d_in[4];
    const float* wv   = (const float*)d_in[5];
    const float* wo   = (const float*)d_in[6];
    float* out = (float*)d_out;

    // Workspace layout (bf16 elems). AO aliases Xb: Xb dead after GEMM1.
    __hip_bfloat16* Xb   = (__hip_bfloat16*)d_ws;
    __hip_bfloat16* Wqkv = Xb   + (size_t)MROWS * DIM;
    __hip_bfloat16* Wob  = Wqkv + (size_t)QKVN * DIM;
    __hip_bfloat16* QKV  = Wob  + (size_t)DIM * DIM;
    __hip_bfloat16* Qp   = QKV  + (size_t)MROWS * QKVN;
    __hip_bfloat16* Kp   = Qp   + (size_t)BATCH * NH * SEQ * HD;
    __hip_bfloat16* Vt   = Kp   + (size_t)BATCH * NKV * SEQ * HD;
    __hip_bfloat16* AO   = Xb;                                  // alias

    cvt_f32_bf16<<<(MROWS * DIM) / 1024, 256, 0, stream>>>(x, Xb, MROWS * DIM);
    cvt_f32_bf16<<<(DIM * DIM) / 1024, 256, 0, stream>>>(wq, Wqkv, DIM * DIM);
    cvt_f32_bf16<<<(NKV * HD * DIM) / 1024, 256, 0, stream>>>(wk, Wqkv + (size_t)DIM * DIM, NKV * HD * DIM);
    cvt_f32_bf16<<<(NKV * HD * DIM) / 1024, 256, 0, stream>>>(wv, Wqkv + (size_t)(DIM + NKV * HD) * DIM, NKV * HD * DIM);
    cvt_f32_bf16<<<(DIM * DIM) / 1024, 256, 0, stream>>>(wo, Wob, DIM * DIM);

    gemm_bt<__hip_bfloat16><<<dim3(MROWS / 128, QKVN / 128), 256, 0, stream>>>(
        Xb, Wqkv, QKV, MROWS, QKVN, DIM);

    rope_qk<<<(BATCH * NH * SEQ * 32) / 256, 256, 0, stream>>>(QKV, fcos, fsin, Qp, NH, 0, 0.125f);
    rope_qk<<<(BATCH * NKV * SEQ * 32) / 256, 256, 0, stream>>>(QKV, fcos, fsin, Kp, NKV, DIM, 1.0f);
    v_repack<<<BATCH * NKV * 32, 256, 0, stream>>>(QKV, Vt);

    flash_attn<<<dim3(SEQ / 64, BATCH * NH), 256, 0, stream>>>(Qp, Kp, Vt, AO);

    gemm_bt<float><<<dim3(MROWS / 128, DIM / 128), 256, 0, stream>>>(
        AO, Wob, out, MROWS, DIM, DIM);
}

// Round 12
// 371.535 us; speedup vs baseline: 1.8990x; 1.0405x over previous
//
#include <hip/hip_runtime.h>
#include <hip/hip_bf16.h>
#include <stdint.h>

#define BATCH 2
#define SEQ   2048
#define DIM   2048
#define NH    32
#define NKV   8
#define HD    64
#define QKVN  3072   // DIM + 2*NKV*HD
#define MROWS 4096   // BATCH*SEQ

typedef __bf16 bf16x8 __attribute__((ext_vector_type(8)));
typedef float  f32x4  __attribute__((ext_vector_type(4)));
typedef unsigned short ushort8v __attribute__((ext_vector_type(8)));

typedef __attribute__((address_space(3))) void lds_void;
typedef const __attribute__((address_space(1))) void gbl_void;

__device__ __forceinline__ void gload_lds16(const void* g, void* l) {
    __builtin_amdgcn_global_load_lds((gbl_void*)g, (lds_void*)l, 16, 0, 0);
}

// ---------------- fp32 -> bf16 convert (vectorized) ----------------
__global__ void cvt_f32_bf16(const float* __restrict__ in,
                             __hip_bfloat16* __restrict__ out, int n) {
    int i = (blockIdx.x * 256 + threadIdx.x) * 4;
    if (i >= n) return;
    const float4 v = *reinterpret_cast<const float4*>(in + i);
    union { ushort4 u; __hip_bfloat16 h[4]; } o;
    o.h[0] = __float2bfloat16(v.x);
    o.h[1] = __float2bfloat16(v.y);
    o.h[2] = __float2bfloat16(v.z);
    o.h[3] = __float2bfloat16(v.w);
    *reinterpret_cast<ushort4*>(out + i) = o.u;
}

// ---------------- GEMM: C[M,N] = A[M,K] * B[N,K]^T  (m97 structure) -----
// + T1 XCD-aware bijective block swizzle (launches guarantee nwg % 8 == 0):
//   each XCD gets a contiguous chunk of tile space -> B-panel L2 reuse.
__device__ __forceinline__ void store_out(float* p, float v) { *p = v; }
__device__ __forceinline__ void store_out(__hip_bfloat16* p, float v) { *p = __float2bfloat16(v); }

template <typename OUT_T>
__global__ __launch_bounds__(256) void gemm_bt(
    const __hip_bfloat16* __restrict__ A,
    const __hip_bfloat16* __restrict__ B,
    OUT_T* __restrict__ C,
    int M, int N, int K)
{
    __shared__ __align__(16) __hip_bfloat16 As[128 * 32];
    __shared__ __align__(16) __hip_bfloat16 Bs[128 * 32];
    const int tid  = threadIdx.x;
    const int lane = tid & 63;
    const int wave = tid >> 6;
    const int wr = wave >> 1, wc = wave & 1;
    const int lr = lane & 15, lg = lane >> 4;

    const int nwg = (int)(gridDim.x * gridDim.y);
    const int id  = (int)blockIdx.y * (int)gridDim.x + (int)blockIdx.x;
    const int cpx = nwg >> 3;
    const int sw  = (id & 7) * cpx + (id >> 3);
    const size_t tm = (size_t)(sw % (int)gridDim.x) * 128;
    const size_t tn = (size_t)(sw / (int)gridDim.x) * 128;

    f32x4 acc[4][4] = {};

    const int srow  = tid >> 2;        // 0..63
    const int scol  = (tid & 3) * 8;   // elem offset in K-step
    const int wbase = wave * 512;      // elems (1024B per wave chunk)

    const __hip_bfloat16* pa = As + (wr * 64 + lr) * 32 + lg * 8;
    const __hip_bfloat16* pb = Bs + (wc * 64 + lr) * 32 + lg * 8;

    for (int k0 = 0; k0 < K; k0 += 32) {
        const __hip_bfloat16* gA = A + (tm + srow) * (size_t)K + k0 + scol;
        const __hip_bfloat16* gB = B + (tn + srow) * (size_t)K + k0 + scol;
        gload_lds16(gA,                 (void*)(As + wbase));
        gload_lds16(gA + (size_t)64*K,  (void*)(As + 2048 + wbase));
        gload_lds16(gB,                 (void*)(Bs + wbase));
        gload_lds16(gB + (size_t)64*K,  (void*)(Bs + 2048 + wbase));
        __syncthreads();   // compiler drains vmcnt before s_barrier
        bf16x8 af[4], bfr[4];
        #pragma unroll
        for (int m = 0; m < 4; ++m) af[m]  = *reinterpret_cast<const bf16x8*>(pa + m * 512);
        #pragma unroll
        for (int n = 0; n < 4; ++n) bfr[n] = *reinterpret_cast<const bf16x8*>(pb + n * 512);
        #pragma unroll
        for (int m = 0; m < 4; ++m)
            #pragma unroll
            for (int n = 0; n < 4; ++n)
                acc[m][n] = __builtin_amdgcn_mfma_f32_16x16x32_bf16(af[m], bfr[n], acc[m][n], 0, 0, 0);
        __syncthreads();
    }

    #pragma unroll
    for (int m = 0; m < 4; ++m)
        #pragma unroll
        for (int n = 0; n < 4; ++n)
            #pragma unroll
            for (int r = 0; r < 4; ++r) {
                size_t row = tm + wr * 64 + m * 16 + lg * 4 + r;
                size_t col = tn + wc * 64 + n * 16 + lr;
                store_out(&C[row * (size_t)N + col], acc[m][n][r]);
            }
}

// ---------------- RoPE (interleaved pairs) + repack ----------------
__global__ void rope_qk(const __hip_bfloat16* __restrict__ qkv,
                        const float* __restrict__ fcos,
                        const float* __restrict__ fsin,
                        __hip_bfloat16* __restrict__ outp,
                        int nheads, int col_off, float mul) {
    int idx = blockIdx.x * 256 + threadIdx.x;
    int i  = idx & 31;
    int s  = (idx >> 5) & (SEQ - 1);
    int bh = idx >> 16;             // SEQ*32 = 65536
    int h  = bh % nheads;
    const __hip_bfloat16* src = qkv + ((size_t)(bh / nheads) * SEQ + s) * QKVN
                                    + col_off + h * HD + 2 * i;
    union { unsigned int u; __hip_bfloat16 h2[2]; } in_, out_;
    in_.u = *reinterpret_cast<const unsigned int*>(src);
    float t0 = __bfloat162float(in_.h2[0]);
    float t1 = __bfloat162float(in_.h2[1]);
    float c  = fcos[s * 32 + i] * mul;
    float sn = fsin[s * 32 + i] * mul;
    out_.h2[0] = __float2bfloat16(t0 * c - t1 * sn);
    out_.h2[1] = __float2bfloat16(t0 * sn + t1 * c);
    *reinterpret_cast<unsigned int*>(outp + ((size_t)bh * SEQ + s) * HD + 2 * i) = out_.u;
}

// V: [b][s][2560 + kh*64 + d] -> Vt[b][kh][d][s]  (LDS tile transpose)
__global__ __launch_bounds__(256) void v_repack(const __hip_bfloat16* __restrict__ qkv,
                                                __hip_bfloat16* __restrict__ vt) {
    __shared__ unsigned short tile[64][66];
    int blk = blockIdx.x;              // 2*8*32 = 512
    int st = blk & 31;
    int kh = (blk >> 5) & 7;
    int b  = blk >> 8;
    int s0 = st * 64;
    int t  = threadIdx.x;
    int r  = t >> 2;
    #pragma unroll
    for (int it = 0; it < 2; ++it) {
        int chunk = (t & 3) + it * 4;   // 0..7
        const __hip_bfloat16* src = qkv + ((size_t)(b * SEQ + s0 + r)) * QKVN
                                        + 2560 + kh * HD + chunk * 8;
        ushort8v v = *reinterpret_cast<const ushort8v*>(src);
        #pragma unroll
        for (int j = 0; j < 8; ++j) tile[r][chunk * 8 + j] = v[j];
    }
    __syncthreads();
    int d = t >> 2;
    #pragma unroll
    for (int it = 0; it < 2; ++it) {
        int chunk = (t & 3) + it * 4;
        ushort8v w;
        #pragma unroll
        for (int j = 0; j < 8; ++j) w[j] = tile[chunk * 8 + j][d];
        *reinterpret_cast<ushort8v*>(vt + ((size_t)(b * NKV + kh) * HD + d) * SEQ
                                        + s0 + chunk * 8) = w;
    }
}

__device__ __forceinline__ unsigned pack_bf16x2(float lo, float hi) {
    __hip_bfloat162 t;
    t.x = __float2bfloat16(lo);
    t.y = __float2bfloat16(hi);
    return *reinterpret_cast<unsigned*>(&t);
}

// ---------------- causal GQA flash attention (LDS-staged K/V) ----------------
// Round-7: 138us, VALUBusy 30%, ~8 dependent ds_bpermute (shfl) per tile on
// the serial chain. This round: defer-max (T13) + lazy-l -> common path has
// ZERO cross-lane ops (rescale/reduce only when a lane's partial max grows
// past m+8; l kept as per-lane partial, reduced once in epilogue).
__global__ __launch_bounds__(256, 4) void flash_attn(
    const __hip_bfloat16* __restrict__ Qp,   // [B][NH][S][HD] (pre-scaled by 0.125)
    const __hip_bfloat16* __restrict__ Kp,   // [B][NKV][S][HD]
    const __hip_bfloat16* __restrict__ Vt,   // [B][NKV][HD][S]
    __hip_bfloat16* __restrict__ O) {        // [B][S][NH*HD]
    __shared__ __align__(16) __hip_bfloat16 Kst[2][4096];   // 2 x 8KB
    __shared__ __align__(16) __hip_bfloat16 Vst[2][4096];   // 2 x 8KB
    __shared__ __align__(16) unsigned char Plds[4][2048];   // per-wave P
    const int qt   = (int)gridDim.x - 1 - (int)blockIdx.x;
    const int bh   = blockIdx.y;
    const int b    = bh >> 5, h = bh & 31;
    const int kvh  = h >> 2;
    const int tid  = threadIdx.x;
    const int wave = tid >> 6, lane = tid & 63;
    const int lr = lane & 15, lg = lane >> 4;
    const int qw0 = qt * 64 + wave * 16;

    // Q as B-operand fragments
    const __hip_bfloat16* qbase = Qp + (((size_t)bh) * SEQ + qw0 + lr) * HD + lg * 8;
    const bf16x8 qa0 = *reinterpret_cast<const bf16x8*>(qbase);
    const bf16x8 qa1 = *reinterpret_cast<const bf16x8*>(qbase + 32);

    const __hip_bfloat16* kb = Kp + ((size_t)(b * NKV + kvh) * SEQ) * HD;
    const __hip_bfloat16* vb = Vt + ((size_t)(b * NKV + kvh) * HD) * SEQ;

    // ---- staging geometry (per thread) ----
    const int srow = tid >> 3;                 // 0..31
    const int sch  = (tid & 7) ^ (srow & 7);   // pre-swizzled 16B chunk in row
    const size_t koff0 = (size_t)srow        * HD  + sch * 8;
    const size_t koff1 = (size_t)(srow + 32) * HD  + sch * 8;
    const size_t voff0 = (size_t)srow        * SEQ + sch * 8;
    const size_t voff1 = (size_t)(srow + 32) * SEQ + sch * 8;
    const int wvb = wave * 1024;               // LDS byte base per wave issue

    // ---- fragment ds_read offsets (elems), kv0-invariant ----
    int foff[4][2];
    #pragma unroll
    for (int g = 0; g < 4; ++g)
        #pragma unroll
        for (int c = 0; c < 2; ++c)
            foff[g][c] = (g * 16 + lr) * 64 + (((c * 4 + lg) ^ (lr & 7)) * 8);

    f32x4 acc[4] = {};          // O[q=qw0+lg*4+r][d=nd*16+lr]
    float m_run = -1e30f;       // row-uniform running max (q = qw0+lr)
    float l_run = 0.f;          // per-lane PARTIAL sum (this lane's k-subset)

    unsigned char* pw = &Plds[wave][0];
    const int swz = (lr & 7) << 4;
    const int kv_end = qt * 64 + 64;

    // prologue: stage first tile into buf 0
    {
        char* kd = (char*)&Kst[0][0];
        char* vd = (char*)&Vst[0][0];
        gload_lds16(kb + koff0, kd + wvb);
        gload_lds16(kb + koff1, kd + 4096 + wvb);
        gload_lds16(vb + voff0, vd + wvb);
        gload_lds16(vb + voff1, vd + 4096 + wvb);
    }
    int cur = 0;

    for (int kv0 = 0; kv0 < kv_end; kv0 += 64) {
        __syncthreads();    // drains staging of buf[cur]
        if (kv0 + 64 < kv_end) {   // prefetch next tile into buf[cur^1]
            const __hip_bfloat16* ks = kb + (size_t)(kv0 + 64) * HD;
            const __hip_bfloat16* vs = vb + (kv0 + 64);
            char* kd = (char*)&Kst[cur ^ 1][0];
            char* vd = (char*)&Vst[cur ^ 1][0];
            gload_lds16(ks + koff0, kd + wvb);
            gload_lds16(ks + koff1, kd + 4096 + wvb);
            gload_lds16(vs + voff0, vd + wvb);
            gload_lds16(vs + voff1, vd + 4096 + wvb);
        }
        const __hip_bfloat16* Kl = &Kst[cur][0];
        const __hip_bfloat16* Vl = &Vst[cur][0];

        // S^T tile: s[nk][r] = S[q=qw0+lr][k=kv0+nk*16+lg*4+r]
        f32x4 s[4];
        #pragma unroll
        for (int nk = 0; nk < 4; ++nk) {
            bf16x8 k0 = *reinterpret_cast<const bf16x8*>(Kl + foff[nk][0]);
            bf16x8 k1 = *reinterpret_cast<const bf16x8*>(Kl + foff[nk][1]);
            f32x4 z = {0.f, 0.f, 0.f, 0.f};
            z = __builtin_amdgcn_mfma_f32_16x16x32_bf16(k0, qa0, z, 0, 0, 0);
            z = __builtin_amdgcn_mfma_f32_16x16x32_bf16(k1, qa1, z, 0, 0, 0);
            s[nk] = z;
        }
        if (kv0 + 64 >= kv_end) {   // last tile only (earlier tiles provably unmasked)
            const int qg = qw0 + lr;
            #pragma unroll
            for (int nk = 0; nk < 4; ++nk) {
                const int kbase = kv0 + nk * 16 + lg * 4;
                #pragma unroll
                for (int r = 0; r < 4; ++r)
                    if (kbase + r > qg) s[nk][r] = -1e30f;
            }
        }
        // in-lane partial max over this lane's 16 k's
        float pmax = fmaxf(fmaxf(s[0][0], s[0][1]), fmaxf(s[0][2], s[0][3]));
        #pragma unroll
        for (int nk = 1; nk < 4; ++nk)
            pmax = fmaxf(pmax, fmaxf(fmaxf(s[nk][0], s[nk][1]), fmaxf(s[nk][2], s[nk][3])));
        // defer-max (T13): rescale only when some lane's partial max > m+8.
        // Uniform branch (__all). P bounded by e^8 -> bf16/fp32 safe.
        if (!__all(pmax - m_run <= 8.0f)) {
            float tmax = fmaxf(pmax, __shfl_xor(pmax, 16, 64));
            tmax = fmaxf(tmax, __shfl_xor(tmax, 32, 64));
            const float mn    = fmaxf(m_run, tmax);
            const float alpha = __expf(m_run - mn);
            m_run = mn;
            l_run *= alpha;     // per-lane partial, lane-local rescale
            const float a0 = __shfl(alpha, lg * 4 + 0, 64);
            const float a1 = __shfl(alpha, lg * 4 + 1, 64);
            const float a2 = __shfl(alpha, lg * 4 + 2, 64);
            const float a3 = __shfl(alpha, lg * 4 + 3, 64);
            #pragma unroll
            for (int nd = 0; nd < 4; ++nd) {
                acc[nd][0] *= a0; acc[nd][1] *= a1;
                acc[nd][2] *= a2; acc[nd][3] *= a3;
            }
        }
        // p = exp(s - m), pack bf16 pairs, swizzled b64 write, in-lane sum
        float tsum = 0.f;
        #pragma unroll
        for (int nk = 0; nk < 4; ++nk) {
            float p0 = __expf(s[nk][0] - m_run);
            float p1 = __expf(s[nk][1] - m_run);
            float p2 = __expf(s[nk][2] - m_run);
            float p3 = __expf(s[nk][3] - m_run);
            tsum += (p0 + p1) + (p2 + p3);
            uint2 pk;
            pk.x = pack_bf16x2(p0, p1);
            pk.y = pack_bf16x2(p2, p3);
            *reinterpret_cast<uint2*>(pw + lr * 128 + ((nk * 32 + lg * 8) ^ swz)) = pk;
        }
        l_run += tsum;      // lazy-l: no cross-lane reduce here
        asm volatile("s_waitcnt lgkmcnt(0)" ::: "memory");
        __builtin_amdgcn_sched_barrier(0);
        // PV A-frags: P[q=lr][k = c*32 + lg*8 .. +7] (swizzle-matched 16B reads)
        const bf16x8 pa0 = *reinterpret_cast<const bf16x8*>(pw + lr * 128 + ((     lg * 16) ^ swz));
        const bf16x8 pa1 = *reinterpret_cast<const bf16x8*>(pw + lr * 128 + ((64 + lg * 16) ^ swz));
        #pragma unroll
        for (int nd = 0; nd < 4; ++nd) {
            bf16x8 v0 = *reinterpret_cast<const bf16x8*>(Vl + foff[nd][0]);
            bf16x8 v1 = *reinterpret_cast<const bf16x8*>(Vl + foff[nd][1]);
            acc[nd] = __builtin_amdgcn_mfma_f32_16x16x32_bf16(pa0, v0, acc[nd], 0, 0, 0);
            acc[nd] = __builtin_amdgcn_mfma_f32_16x16x32_bf16(pa1, v1, acc[nd], 0, 0, 0);
        }
        cur ^= 1;
    }
    // epilogue: reduce the per-lane l partials across the 4 lanes of each row,
    // then broadcast to the D-layout lanes.
    float lt = l_run;
    lt += __shfl_xor(lt, 16, 64);
    lt += __shfl_xor(lt, 32, 64);
    float linv[4];
    #pragma unroll
    for (int r = 0; r < 4; ++r)
        linv[r] = 1.f / __shfl(lt, lg * 4 + r, 64);
    #pragma unroll
    for (int nd = 0; nd < 4; ++nd)
        #pragma unroll
        for (int r = 0; r < 4; ++r) {
            int qg  = qw0 + lg * 4 + r;
            int col = h * HD + nd * 16 + lr;
            O[((size_t)(b * SEQ + qg)) * DIM + col] = __float2bfloat16(acc[nd][r] * linv[r]);
        }
}

// ---------------- launch ----------------
extern "C" void kernel_launch(void* const* d_in, const int* in_sizes, int n_in,
                              void* d_out, int out_size, void* d_ws, size_t ws_size,
                              hipStream_t stream) {
    const float* x    = (const float*)d_in[0];
    const float* fcos = (const float*)d_in[1];
    const float* fsin = (const float*)d_in[2];
    const float* wq   = (const float*)d_in[3];
    const float* wk   = (const float*)d_in[4];
    const float* wv   = (const float*)d_in[5];
    const float* wo   = (const float*)d_in[6];
    float* out = (float*)d_out;

    // Workspace layout (bf16 elems). AO aliases Xb: Xb dead after GEMM1.
    __hip_bfloat16* Xb   = (__hip_bfloat16*)d_ws;
    __hip_bfloat16* Wqkv = Xb   + (size_t)MROWS * DIM;
    __hip_bfloat16* Wob  = Wqkv + (size_t)QKVN * DIM;
    __hip_bfloat16* QKV  = Wob  + (size_t)DIM * DIM;
    __hip_bfloat16* Qp   = QKV  + (size_t)MROWS * QKVN;
    __hip_bfloat16* Kp   = Qp   + (size_t)BATCH * NH * SEQ * HD;
    __hip_bfloat16* Vt   = Kp   + (size_t)BATCH * NKV * SEQ * HD;
    __hip_bfloat16* AO   = Xb;                                  // alias

    cvt_f32_bf16<<<(MROWS * DIM) / 1024, 256, 0, stream>>>(x, Xb, MROWS * DIM);
    cvt_f32_bf16<<<(DIM * DIM) / 1024, 256, 0, stream>>>(wq, Wqkv, DIM * DIM);
    cvt_f32_bf16<<<(NKV * HD * DIM) / 1024, 256, 0, stream>>>(wk, Wqkv + (size_t)DIM * DIM, NKV * HD * DIM);
    cvt_f32_bf16<<<(NKV * HD * DIM) / 1024, 256, 0, stream>>>(wv, Wqkv + (size_t)(DIM + NKV * HD) * DIM, NKV * HD * DIM);
    cvt_f32_bf16<<<(DIM * DIM) / 1024, 256, 0, stream>>>(wo, Wob, DIM * DIM);

    gemm_bt<__hip_bfloat16><<<dim3(MROWS / 128, QKVN / 128), 256, 0, stream>>>(
        Xb, Wqkv, QKV, MROWS, QKVN, DIM);

    rope_qk<<<(BATCH * NH * SEQ * 32) / 256, 256, 0, stream>>>(QKV, fcos, fsin, Qp, NH, 0, 0.125f);
    rope_qk<<<(BATCH * NKV * SEQ * 32) / 256, 256, 0, stream>>>(QKV, fcos, fsin, Kp, NKV, DIM, 1.0f);
    v_repack<<<BATCH * NKV * 32, 256, 0, stream>>>(QKV, Vt);

    flash_attn<<<dim3(SEQ / 64, BATCH * NH), 256, 0, stream>>>(Qp, Kp, Vt, AO);

    gemm_bt<float><<<dim3(MROWS / 128, DIM / 128), 256, 0, stream>>>(
        AO, Wob, out, MROWS, DIM, DIM);
}

// Round 13
// 355.128 us; speedup vs baseline: 1.9867x; 1.0462x over previous
//
#include <hip/hip_runtime.h>
#include <hip/hip_bf16.h>
#include <stdint.h>

#define BATCH 2
#define SEQ   2048
#define DIM   2048
#define NH    32
#define NKV   8
#define HD    64
#define QKVN  3072   // DIM + 2*NKV*HD
#define MROWS 4096   // BATCH*SEQ

typedef __bf16 bf16x8 __attribute__((ext_vector_type(8)));
typedef float  f32x4  __attribute__((ext_vector_type(4)));
typedef unsigned short ushort8v __attribute__((ext_vector_type(8)));

typedef __attribute__((address_space(3))) void lds_void;
typedef const __attribute__((address_space(1))) void gbl_void;

__device__ __forceinline__ void gload_lds16(const void* g, void* l) {
    __builtin_amdgcn_global_load_lds((gbl_void*)g, (lds_void*)l, 16, 0, 0);
}

__device__ __forceinline__ void cvt4(const float* src, __hip_bfloat16* dst) {
    const float4 v = *reinterpret_cast<const float4*>(src);
    union { ushort4 u; __hip_bfloat16 h[4]; } o;
    o.h[0] = __float2bfloat16(v.x);
    o.h[1] = __float2bfloat16(v.y);
    o.h[2] = __float2bfloat16(v.z);
    o.h[3] = __float2bfloat16(v.w);
    *reinterpret_cast<ushort4*>(dst) = o.u;
}

// ---------------- fp32 -> bf16 convert (vectorized) ----------------
__global__ void cvt_f32_bf16(const float* __restrict__ in,
                             __hip_bfloat16* __restrict__ out, int n) {
    int i = (blockIdx.x * 256 + threadIdx.x) * 4;
    if (i >= n) return;
    cvt4(in + i, out + i);
}

// All 4 weight matrices -> one contiguous bf16 region (Wqkv ++ Wob).
// Range boundaries all divisible by 4 -> each thread's chunk is single-source.
__global__ void cvt_weights(const float* __restrict__ wq,
                            const float* __restrict__ wk,
                            const float* __restrict__ wv,
                            const float* __restrict__ wo,
                            __hip_bfloat16* __restrict__ out) {
    const int E0 = DIM * DIM;              // wq end
    const int E1 = E0 + NKV * HD * DIM;    // wk end
    const int E2 = E1 + NKV * HD * DIM;    // wv end
    int i = (blockIdx.x * 256 + threadIdx.x) * 4;
    const float* src;
    int off;
    if      (i < E0) { src = wq; off = i; }
    else if (i < E1) { src = wk; off = i - E0; }
    else if (i < E2) { src = wv; off = i - E1; }
    else             { src = wo; off = i - E2; }
    cvt4(src + off, out + i);
}

// ---------------- GEMM: C[M,N] = A[M,K] * B[N,K]^T ----------------
// m97 fragment structure + T1 XCD swizzle + DOUBLE-BUFFERED 2-phase K-loop
// (T3-minimum): stage(next) issued BEFORE compute(cur); one barrier/K-step.
// Round-12 diagnosis: single-buffered stage->sync exposed full staging
// latency every K-step at only ~3 blocks/CU grid occupancy.
__device__ __forceinline__ void store_out(float* p, float v) { *p = v; }
__device__ __forceinline__ void store_out(__hip_bfloat16* p, float v) { *p = __float2bfloat16(v); }

template <typename OUT_T>
__global__ __launch_bounds__(256) void gemm_bt(
    const __hip_bfloat16* __restrict__ A,
    const __hip_bfloat16* __restrict__ B,
    OUT_T* __restrict__ C,
    int M, int N, int K)
{
    __shared__ __align__(16) __hip_bfloat16 As[2][128 * 32];
    __shared__ __align__(16) __hip_bfloat16 Bs[2][128 * 32];
    const int tid  = threadIdx.x;
    const int lane = tid & 63;
    const int wave = tid >> 6;
    const int wr = wave >> 1, wc = wave & 1;
    const int lr = lane & 15, lg = lane >> 4;

    const int nwg = (int)(gridDim.x * gridDim.y);
    const int id  = (int)blockIdx.y * (int)gridDim.x + (int)blockIdx.x;
    const int cpx = nwg >> 3;
    const int sw  = (id & 7) * cpx + (id >> 3);
    const size_t tm = (size_t)(sw % (int)gridDim.x) * 128;
    const size_t tn = (size_t)(sw / (int)gridDim.x) * 128;

    f32x4 acc[4][4] = {};

    const int srow  = tid >> 2;        // 0..63
    const int scol  = (tid & 3) * 8;   // elem offset in K-step
    const int wbase = wave * 512;      // elems (1024B per wave chunk)

    const __hip_bfloat16* gA0 = A + (tm + srow) * (size_t)K + scol;
    const __hip_bfloat16* gB0 = B + (tn + srow) * (size_t)K + scol;

    // prologue: stage k0=0 into buf 0
    gload_lds16(gA0,                 (void*)(As[0] + wbase));
    gload_lds16(gA0 + (size_t)64*K,  (void*)(As[0] + 2048 + wbase));
    gload_lds16(gB0,                 (void*)(Bs[0] + wbase));
    gload_lds16(gB0 + (size_t)64*K,  (void*)(Bs[0] + 2048 + wbase));
    int cur = 0;

    for (int k0 = 0; k0 < K; k0 += 32) {
        __syncthreads();   // drains staging of buf[cur] (issued one compute ago)
        if (k0 + 32 < K) { // prefetch next K-step into buf[cur^1]
            gload_lds16(gA0 + k0 + 32,                (void*)(As[cur ^ 1] + wbase));
            gload_lds16(gA0 + (size_t)64*K + k0 + 32, (void*)(As[cur ^ 1] + 2048 + wbase));
            gload_lds16(gB0 + k0 + 32,                (void*)(Bs[cur ^ 1] + wbase));
            gload_lds16(gB0 + (size_t)64*K + k0 + 32, (void*)(Bs[cur ^ 1] + 2048 + wbase));
        }
        const __hip_bfloat16* pa = As[cur] + (wr * 64 + lr) * 32 + lg * 8;
        const __hip_bfloat16* pb = Bs[cur] + (wc * 64 + lr) * 32 + lg * 8;
        bf16x8 af[4], bfr[4];
        #pragma unroll
        for (int m = 0; m < 4; ++m) af[m]  = *reinterpret_cast<const bf16x8*>(pa + m * 512);
        #pragma unroll
        for (int n = 0; n < 4; ++n) bfr[n] = *reinterpret_cast<const bf16x8*>(pb + n * 512);
        #pragma unroll
        for (int m = 0; m < 4; ++m)
            #pragma unroll
            for (int n = 0; n < 4; ++n)
                acc[m][n] = __builtin_amdgcn_mfma_f32_16x16x32_bf16(af[m], bfr[n], acc[m][n], 0, 0, 0);
        cur ^= 1;
    }

    #pragma unroll
    for (int m = 0; m < 4; ++m)
        #pragma unroll
        for (int n = 0; n < 4; ++n)
            #pragma unroll
            for (int r = 0; r < 4; ++r) {
                size_t row = tm + wr * 64 + m * 16 + lg * 4 + r;
                size_t col = tn + wc * 64 + n * 16 + lr;
                store_out(&C[row * (size_t)N + col], acc[m][n][r]);
            }
}

// ---------------- RoPE (interleaved pairs), Q and K fused ----------------
// Q part: first BATCH*NH*SEQ*32 indices (mul=0.125 folds 1/sqrt(HD), exact
// pow2 -> no added rounding); K part: remainder. Block-uniform branch
// (QTOT divisible by 256).
__global__ void rope_fused(const __hip_bfloat16* __restrict__ qkv,
                           const float* __restrict__ fcos,
                           const float* __restrict__ fsin,
                           __hip_bfloat16* __restrict__ Qp,
                           __hip_bfloat16* __restrict__ Kp) {
    int idx = blockIdx.x * 256 + threadIdx.x;
    const int QTOT = BATCH * NH * SEQ * 32;
    int nheads, col_off; float mul; __hip_bfloat16* outp;
    if (idx < QTOT) { nheads = NH;  col_off = 0;   mul = 0.125f; outp = Qp; }
    else { idx -= QTOT; nheads = NKV; col_off = DIM; mul = 1.0f; outp = Kp; }
    int i  = idx & 31;
    int s  = (idx >> 5) & (SEQ - 1);
    int bh = idx >> 16;             // SEQ*32 = 65536
    int h  = bh % nheads;
    const __hip_bfloat16* src = qkv + ((size_t)(bh / nheads) * SEQ + s) * QKVN
                                    + col_off + h * HD + 2 * i;
    union { unsigned int u; __hip_bfloat16 h2[2]; } in_, out_;
    in_.u = *reinterpret_cast<const unsigned int*>(src);
    float t0 = __bfloat162float(in_.h2[0]);
    float t1 = __bfloat162float(in_.h2[1]);
    float c  = fcos[s * 32 + i] * mul;
    float sn = fsin[s * 32 + i] * mul;
    out_.h2[0] = __float2bfloat16(t0 * c - t1 * sn);
    out_.h2[1] = __float2bfloat16(t0 * sn + t1 * c);
    *reinterpret_cast<unsigned int*>(outp + ((size_t)bh * SEQ + s) * HD + 2 * i) = out_.u;
}

// V: [b][s][2560 + kh*64 + d] -> Vt[b][kh][d][s]  (LDS tile transpose)
__global__ __launch_bounds__(256) void v_repack(const __hip_bfloat16* __restrict__ qkv,
                                                __hip_bfloat16* __restrict__ vt) {
    __shared__ unsigned short tile[64][66];
    int blk = blockIdx.x;              // 2*8*32 = 512
    int st = blk & 31;
    int kh = (blk >> 5) & 7;
    int b  = blk >> 8;
    int s0 = st * 64;
    int t  = threadIdx.x;
    int r  = t >> 2;
    #pragma unroll
    for (int it = 0; it < 2; ++it) {
        int chunk = (t & 3) + it * 4;   // 0..7
        const __hip_bfloat16* src = qkv + ((size_t)(b * SEQ + s0 + r)) * QKVN
                                        + 2560 + kh * HD + chunk * 8;
        ushort8v v = *reinterpret_cast<const ushort8v*>(src);
        #pragma unroll
        for (int j = 0; j < 8; ++j) tile[r][chunk * 8 + j] = v[j];
    }
    __syncthreads();
    int d = t >> 2;
    #pragma unroll
    for (int it = 0; it < 2; ++it) {
        int chunk = (t & 3) + it * 4;
        ushort8v w;
        #pragma unroll
        for (int j = 0; j < 8; ++j) w[j] = tile[chunk * 8 + j][d];
        *reinterpret_cast<ushort8v*>(vt + ((size_t)(b * NKV + kh) * HD + d) * SEQ
                                        + s0 + chunk * 8) = w;
    }
}

__device__ __forceinline__ unsigned pack_bf16x2(float lo, float hi) {
    __hip_bfloat162 t;
    t.x = __float2bfloat16(lo);
    t.y = __float2bfloat16(hi);
    return *reinterpret_cast<unsigned*>(&t);
}

// ---------------- causal GQA flash attention (LDS-staged K/V) ----------------
// Validated r12: 118us, defer-max + lazy-l (zero cross-lane common path).
// Unchanged this round.
__global__ __launch_bounds__(256, 4) void flash_attn(
    const __hip_bfloat16* __restrict__ Qp,   // [B][NH][S][HD] (pre-scaled by 0.125)
    const __hip_bfloat16* __restrict__ Kp,   // [B][NKV][S][HD]
    const __hip_bfloat16* __restrict__ Vt,   // [B][NKV][HD][S]
    __hip_bfloat16* __restrict__ O) {        // [B][S][NH*HD]
    __shared__ __align__(16) __hip_bfloat16 Kst[2][4096];   // 2 x 8KB
    __shared__ __align__(16) __hip_bfloat16 Vst[2][4096];   // 2 x 8KB
    __shared__ __align__(16) unsigned char Plds[4][2048];   // per-wave P
    const int qt   = (int)gridDim.x - 1 - (int)blockIdx.x;
    const int bh   = blockIdx.y;
    const int b    = bh >> 5, h = bh & 31;
    const int kvh  = h >> 2;
    const int tid  = threadIdx.x;
    const int wave = tid >> 6, lane = tid & 63;
    const int lr = lane & 15, lg = lane >> 4;
    const int qw0 = qt * 64 + wave * 16;

    const __hip_bfloat16* qbase = Qp + (((size_t)bh) * SEQ + qw0 + lr) * HD + lg * 8;
    const bf16x8 qa0 = *reinterpret_cast<const bf16x8*>(qbase);
    const bf16x8 qa1 = *reinterpret_cast<const bf16x8*>(qbase + 32);

    const __hip_bfloat16* kb = Kp + ((size_t)(b * NKV + kvh) * SEQ) * HD;
    const __hip_bfloat16* vb = Vt + ((size_t)(b * NKV + kvh) * HD) * SEQ;

    const int srow = tid >> 3;                 // 0..31
    const int sch  = (tid & 7) ^ (srow & 7);   // pre-swizzled 16B chunk in row
    const size_t koff0 = (size_t)srow        * HD  + sch * 8;
    const size_t koff1 = (size_t)(srow + 32) * HD  + sch * 8;
    const size_t voff0 = (size_t)srow        * SEQ + sch * 8;
    const size_t voff1 = (size_t)(srow + 32) * SEQ + sch * 8;
    const int wvb = wave * 1024;               // LDS byte base per wave issue

    int foff[4][2];
    #pragma unroll
    for (int g = 0; g < 4; ++g)
        #pragma unroll
        for (int c = 0; c < 2; ++c)
            foff[g][c] = (g * 16 + lr) * 64 + (((c * 4 + lg) ^ (lr & 7)) * 8);

    f32x4 acc[4] = {};          // O[q=qw0+lg*4+r][d=nd*16+lr]
    float m_run = -1e30f;       // row-uniform running max (q = qw0+lr)
    float l_run = 0.f;          // per-lane PARTIAL sum (this lane's k-subset)

    unsigned char* pw = &Plds[wave][0];
    const int swz = (lr & 7) << 4;
    const int kv_end = qt * 64 + 64;

    {
        char* kd = (char*)&Kst[0][0];
        char* vd = (char*)&Vst[0][0];
        gload_lds16(kb + koff0, kd + wvb);
        gload_lds16(kb + koff1, kd + 4096 + wvb);
        gload_lds16(vb + voff0, vd + wvb);
        gload_lds16(vb + voff1, vd + 4096 + wvb);
    }
    int cur = 0;

    for (int kv0 = 0; kv0 < kv_end; kv0 += 64) {
        __syncthreads();    // drains staging of buf[cur]
        if (kv0 + 64 < kv_end) {   // prefetch next tile into buf[cur^1]
            const __hip_bfloat16* ks = kb + (size_t)(kv0 + 64) * HD;
            const __hip_bfloat16* vs = vb + (kv0 + 64);
            char* kd = (char*)&Kst[cur ^ 1][0];
            char* vd = (char*)&Vst[cur ^ 1][0];
            gload_lds16(ks + koff0, kd + wvb);
            gload_lds16(ks + koff1, kd + 4096 + wvb);
            gload_lds16(vs + voff0, vd + wvb);
            gload_lds16(vs + voff1, vd + 4096 + wvb);
        }
        const __hip_bfloat16* Kl = &Kst[cur][0];
        const __hip_bfloat16* Vl = &Vst[cur][0];

        f32x4 s[4];
        #pragma unroll
        for (int nk = 0; nk < 4; ++nk) {
            bf16x8 k0 = *reinterpret_cast<const bf16x8*>(Kl + foff[nk][0]);
            bf16x8 k1 = *reinterpret_cast<const bf16x8*>(Kl + foff[nk][1]);
            f32x4 z = {0.f, 0.f, 0.f, 0.f};
            z = __builtin_amdgcn_mfma_f32_16x16x32_bf16(k0, qa0, z, 0, 0, 0);
            z = __builtin_amdgcn_mfma_f32_16x16x32_bf16(k1, qa1, z, 0, 0, 0);
            s[nk] = z;
        }
        if (kv0 + 64 >= kv_end) {   // last tile only (earlier tiles provably unmasked)
            const int qg = qw0 + lr;
            #pragma unroll
            for (int nk = 0; nk < 4; ++nk) {
                const int kbase = kv0 + nk * 16 + lg * 4;
                #pragma unroll
                for (int r = 0; r < 4; ++r)
                    if (kbase + r > qg) s[nk][r] = -1e30f;
            }
        }
        float pmax = fmaxf(fmaxf(s[0][0], s[0][1]), fmaxf(s[0][2], s[0][3]));
        #pragma unroll
        for (int nk = 1; nk < 4; ++nk)
            pmax = fmaxf(pmax, fmaxf(fmaxf(s[nk][0], s[nk][1]), fmaxf(s[nk][2], s[nk][3])));
        if (!__all(pmax - m_run <= 8.0f)) {
            float tmax = fmaxf(pmax, __shfl_xor(pmax, 16, 64));
            tmax = fmaxf(tmax, __shfl_xor(tmax, 32, 64));
            const float mn    = fmaxf(m_run, tmax);
            const float alpha = __expf(m_run - mn);
            m_run = mn;
            l_run *= alpha;
            const float a0 = __shfl(alpha, lg * 4 + 0, 64);
            const float a1 = __shfl(alpha, lg * 4 + 1, 64);
            const float a2 = __shfl(alpha, lg * 4 + 2, 64);
            const float a3 = __shfl(alpha, lg * 4 + 3, 64);
            #pragma unroll
            for (int nd = 0; nd < 4; ++nd) {
                acc[nd][0] *= a0; acc[nd][1] *= a1;
                acc[nd][2] *= a2; acc[nd][3] *= a3;
            }
        }
        float tsum = 0.f;
        #pragma unroll
        for (int nk = 0; nk < 4; ++nk) {
            float p0 = __expf(s[nk][0] - m_run);
            float p1 = __expf(s[nk][1] - m_run);
            float p2 = __expf(s[nk][2] - m_run);
            float p3 = __expf(s[nk][3] - m_run);
            tsum += (p0 + p1) + (p2 + p3);
            uint2 pk;
            pk.x = pack_bf16x2(p0, p1);
            pk.y = pack_bf16x2(p2, p3);
            *reinterpret_cast<uint2*>(pw + lr * 128 + ((nk * 32 + lg * 8) ^ swz)) = pk;
        }
        l_run += tsum;
        asm volatile("s_waitcnt lgkmcnt(0)" ::: "memory");
        __builtin_amdgcn_sched_barrier(0);
        const bf16x8 pa0 = *reinterpret_cast<const bf16x8*>(pw + lr * 128 + ((     lg * 16) ^ swz));
        const bf16x8 pa1 = *reinterpret_cast<const bf16x8*>(pw + lr * 128 + ((64 + lg * 16) ^ swz));
        #pragma unroll
        for (int nd = 0; nd < 4; ++nd) {
            bf16x8 v0 = *reinterpret_cast<const bf16x8*>(Vl + foff[nd][0]);
            bf16x8 v1 = *reinterpret_cast<const bf16x8*>(Vl + foff[nd][1]);
            acc[nd] = __builtin_amdgcn_mfma_f32_16x16x32_bf16(pa0, v0, acc[nd], 0, 0, 0);
            acc[nd] = __builtin_amdgcn_mfma_f32_16x16x32_bf16(pa1, v1, acc[nd], 0, 0, 0);
        }
        cur ^= 1;
    }
    float lt = l_run;
    lt += __shfl_xor(lt, 16, 64);
    lt += __shfl_xor(lt, 32, 64);
    float linv[4];
    #pragma unroll
    for (int r = 0; r < 4; ++r)
        linv[r] = 1.f / __shfl(lt, lg * 4 + r, 64);
    #pragma unroll
    for (int nd = 0; nd < 4; ++nd)
        #pragma unroll
        for (int r = 0; r < 4; ++r) {
            int qg  = qw0 + lg * 4 + r;
            int col = h * HD + nd * 16 + lr;
            O[((size_t)(b * SEQ + qg)) * DIM + col] = __float2bfloat16(acc[nd][r] * linv[r]);
        }
}

// ---------------- launch ----------------
extern "C" void kernel_launch(void* const* d_in, const int* in_sizes, int n_in,
                              void* d_out, int out_size, void* d_ws, size_t ws_size,
                              hipStream_t stream) {
    const float* x    = (const float*)d_in[0];
    const float* fcos = (const float*)d_in[1];
    const float* fsin = (const float*)d_in[2];
    const float* wq   = (const float*)d_in[3];
    const float* wk   = (const float*)d_in[4];
    const float* wv   = (const float*)d_in[5];
    const float* wo   = (const float*)d_in[6];
    float* out = (float*)d_out;

    // Workspace layout (bf16 elems). AO aliases Xb: Xb dead after GEMM1.
    __hip_bfloat16* Xb   = (__hip_bfloat16*)d_ws;
    __hip_bfloat16* Wqkv = Xb   + (size_t)MROWS * DIM;
    __hip_bfloat16* Wob  = Wqkv + (size_t)QKVN * DIM;   // contiguous after Wqkv
    __hip_bfloat16* QKV  = Wob  + (size_t)DIM * DIM;
    __hip_bfloat16* Qp   = QKV  + (size_t)MROWS * QKVN;
    __hip_bfloat16* Kp   = Qp   + (size_t)BATCH * NH * SEQ * HD;
    __hip_bfloat16* Vt   = Kp   + (size_t)BATCH * NKV * SEQ * HD;
    __hip_bfloat16* AO   = Xb;                                  // alias

    cvt_f32_bf16<<<(MROWS * DIM) / 1024, 256, 0, stream>>>(x, Xb, MROWS * DIM);
    // wq|wk|wv|wo -> Wqkv ++ Wob (contiguous, 10.49M elems)
    cvt_weights<<<(QKVN * DIM + DIM * DIM) / 1024, 256, 0, stream>>>(wq, wk, wv, wo, Wqkv);

    gemm_bt<__hip_bfloat16><<<dim3(MROWS / 128, QKVN / 128), 256, 0, stream>>>(
        Xb, Wqkv, QKV, MROWS, QKVN, DIM);

    rope_fused<<<(BATCH * (NH + NKV) * SEQ * 32) / 256, 256, 0, stream>>>(
        QKV, fcos, fsin, Qp, Kp);
    v_repack<<<BATCH * NKV * 32, 256, 0, stream>>>(QKV, Vt);

    flash_attn<<<dim3(SEQ / 64, BATCH * NH), 256, 0, stream>>>(Qp, Kp, Vt, AO);

    gemm_bt<float><<<dim3(MROWS / 128, DIM / 128), 256, 0, stream>>>(
        AO, Wob, out, MROWS, DIM, DIM);
}